// Round 3
// baseline (1113.581 us; speedup 1.0000x reference)
//
#include <hip/hip_runtime.h>
#include <math.h>

#define N_NODES 50000
#define N_EDGES 1600000
#define EF      (N_EDGES + N_NODES)
#define NSTK    25000
#define IN_DIM  5
#define HID     32
#define HEADS   4
#define NEG_SLOPE 0.2f

#define SCAN_T  1024
#define CHUNK   ((N_NODES + SCAN_T - 1) / SCAN_T)   // 49

// d_out layout (floats): weights[25001] | value[1] | edge_index_full[2*EF] | alpha1[EF*4]
#define OUT_W   0
#define OUT_V   (NSTK + 1)
#define OUT_EIF (NSTK + 2)
#define OUT_A1  (OUT_EIF + 2 * EF)

__device__ __forceinline__ float lrelu(float x) { return x > 0.f ? x : NEG_SLOPE * x; }
__device__ __forceinline__ float elu1(float x)  { return x > 0.f ? x : expf(x) - 1.f; }

// ---------------- fused edge prep ----------------
// One pass over the edge list: dst-degree atomics, ea partial sum, edge_index_full out.
// hdr[0]=ea sum (finalized to mean in scan_scalar), hdr[1..4]=ce1[h], hdr[5]=ce2, hdr[6]=value
__global__ void edge_prep(const int* __restrict__ ei, const float* __restrict__ ea,
                          int* __restrict__ deg, float* __restrict__ out_eif, float* hdr) {
    float s = 0.f;
    for (int e = blockIdx.x * blockDim.x + threadIdx.x; e < EF; e += gridDim.x * blockDim.x) {
        int sv, dv;
        if (e < N_EDGES) {
            sv = ei[e];
            dv = ei[N_EDGES + e];
            s += ea[e];
        } else {
            sv = dv = e - N_EDGES;
        }
        atomicAdd(&deg[dv], 1);
        out_eif[e]      = (float)sv;
        out_eif[EF + e] = (float)dv;
    }
    #pragma unroll
    for (int off = 1; off < 64; off <<= 1) s += __shfl_xor(s, off);
    if ((threadIdx.x & 63) == 0) atomicAdd(&hdr[0], s);
}

// ---------------- scan (serial-chunk) + scalar prep ----------------
// Single block of 1024. Thread t owns nodes [t*CHUNK, (t+1)*CHUNK).
// Threads 0..127 also compute the per-head edge-attention coefficients.
__global__ void scan_scalar(const int* __restrict__ deg, int* __restrict__ rowoff,
                            const float* __restrict__ We1, const float* __restrict__ ae1,
                            const float* __restrict__ We2, const float* __restrict__ ae2,
                            float* hdr) {
    __shared__ int sums[SCAN_T];
    int t = threadIdx.x;

    // scalar prep (edge coefficient dot-products; hdr[0] atomic sum already complete
    // because edge_prep kernel finished before this launch)
    if (t < 128) {
        float p = We1[t] * ae1[t];
        #pragma unroll
        for (int off = 1; off < 32; off <<= 1) p += __shfl_xor(p, off);
        if ((t & 31) == 0) hdr[1 + (t >> 5)] = p;
        if (t < 32) {
            float q = We2[t] * ae2[t];
            #pragma unroll
            for (int off = 1; off < 32; off <<= 1) q += __shfl_xor(q, off);
            if (t == 0) { hdr[5] = q; hdr[0] = hdr[0] / (float)N_EDGES; }
        }
    }

    int base = t * CHUNK;
    int local = 0;
    for (int i = 0; i < CHUNK; i++) {
        int idx = base + i;
        if (idx < N_NODES) local += deg[idx];
    }
    sums[t] = local;
    __syncthreads();
    #pragma unroll
    for (int off = 1; off < SCAN_T; off <<= 1) {
        int v = (t >= off) ? sums[t - off] : 0;
        __syncthreads();
        sums[t] += v;
        __syncthreads();
    }
    int run = sums[t] - local;          // exclusive prefix of this chunk
    if (t == 0) rowoff[0] = 0;
    for (int i = 0; i < CHUNK; i++) {
        int idx = base + i;
        if (idx < N_NODES) { run += deg[idx]; rowoff[idx + 1] = run; }
    }
}

__global__ void fill_csr(const int* __restrict__ ei, const int* __restrict__ rowoff,
                         int* cursor, int* eid) {
    for (int e = blockIdx.x * blockDim.x + threadIdx.x; e < EF; e += gridDim.x * blockDim.x) {
        int d = (e < N_EDGES) ? ei[N_EDGES + e] : (e - N_EDGES);
        int pos = rowoff[d] + atomicAdd(&cursor[d], 1);
        eid[pos] = e;
    }
}

// ---------------- layer 1 linear + attention scalars ----------------
// block = 128 threads, one node per block: h1pre[n,t] = sum_k x[n,k]*W1[k,t]
__global__ void node_lin1(const float* __restrict__ x, const float* __restrict__ W1,
                          const float* __restrict__ as1, const float* __restrict__ ad1,
                          float* __restrict__ h1pre, float* __restrict__ ssrc1,
                          float* __restrict__ sdst1) {
    int n = blockIdx.x, t = threadIdx.x;
    float hv = 0.f;
    #pragma unroll
    for (int k = 0; k < IN_DIM; k++) hv += x[n * IN_DIM + k] * W1[k * 128 + t];
    h1pre[n * 128 + t] = hv;
    float a = hv * as1[t];
    float b = hv * ad1[t];
    #pragma unroll
    for (int off = 1; off < 32; off <<= 1) { a += __shfl_xor(a, off); b += __shfl_xor(b, off); }
    if ((t & 31) == 0) { ssrc1[n * 4 + (t >> 5)] = a; sdst1[n * 4 + (t >> 5)] = b; }
}

// ---------------- layer 1 aggregation (one wave per dst node) ----------------
__global__ void l1_agg(const int* __restrict__ ei, const float* __restrict__ ea,
                       const int* __restrict__ rowoff, const int* __restrict__ eid,
                       const float* __restrict__ ssrc1, const float* __restrict__ sdst1,
                       const float* __restrict__ h1pre, const float* __restrict__ b1,
                       const float* __restrict__ hdr, float* __restrict__ alpha_out,
                       float* __restrict__ h1) {
    int n = blockIdx.x * 4 + (threadIdx.x >> 6);
    if (n >= N_NODES) return;
    int lane = threadIdx.x & 63;
    int start = rowoff[n], deg = rowoff[n + 1] - start;
    int hl = lane & 3;
    float ea_mean = hdr[0];
    float ce = hdr[1 + hl];
    float sd = sdst1[n * 4 + hl];

    float m = -1e30f;
    for (int k = lane; k < deg * 4; k += 64) {
        int e = eid[start + (k >> 2)];
        int s = (e < N_EDGES) ? ei[e] : (e - N_EDGES);
        float eav = (e < N_EDGES) ? ea[e] : ea_mean;
        m = fmaxf(m, lrelu(ssrc1[s * 4 + hl] + sd + eav * ce));
    }
    #pragma unroll
    for (int off = 4; off < 64; off <<= 1) m = fmaxf(m, __shfl_xor(m, off));

    float den = 0.f;
    for (int k = lane; k < deg * 4; k += 64) {
        int e = eid[start + (k >> 2)];
        int s = (e < N_EDGES) ? ei[e] : (e - N_EDGES);
        float eav = (e < N_EDGES) ? ea[e] : ea_mean;
        float p = expf(lrelu(ssrc1[s * 4 + hl] + sd + eav * ce) - m);
        den += p;
        alpha_out[e * 4 + hl] = p;
    }
    #pragma unroll
    for (int off = 4; off < 64; off <<= 1) den += __shfl_xor(den, off);
    float inv = 1.f / (den + 1e-16f);

    // rescale own writes (same-lane same-address store->load: ordered)
    for (int k = lane; k < deg * 4; k += 64) {
        int e = eid[start + (k >> 2)];
        alpha_out[e * 4 + hl] *= inv;
    }

    // weighted accumulation: recompute alpha in-register (avoids cross-lane
    // global store->load visibility hazard). Lane h<4 holds head-h m/inv/sd/ce.
    int i0 = lane, i1 = lane + 64;
    int h0 = i0 >> 5, h1i = i1 >> 5;               // {0,1} and {2,3}
    float m0  = __shfl(m, h0),  m1  = __shfl(m, h1i);
    float v0  = __shfl(inv, h0), v1 = __shfl(inv, h1i);
    float sd0 = __shfl(sd, h0), sd1 = __shfl(sd, h1i);
    float ce0 = __shfl(ce, h0), ce1v = __shfl(ce, h1i);
    float acc0 = 0.f, acc1 = 0.f;
    for (int j = 0; j < deg; j++) {
        int e = eid[start + j];
        int s = (e < N_EDGES) ? ei[e] : (e - N_EDGES);
        float eav = (e < N_EDGES) ? ea[e] : ea_mean;
        float a0 = expf(lrelu(ssrc1[s * 4 + h0]  + sd0 + eav * ce0)  - m0) * v0;
        float a1 = expf(lrelu(ssrc1[s * 4 + h1i] + sd1 + eav * ce1v) - m1) * v1;
        acc0 += a0 * h1pre[s * 128 + i0];
        acc1 += a1 * h1pre[s * 128 + i1];
    }
    h1[n * 128 + i0] = elu1(acc0 + b1[i0]);
    h1[n * 128 + i1] = elu1(acc1 + b1[i1]);
}

// ---------------- layer 2 linear + attention scalars ----------------
__global__ void node_lin2(const float* __restrict__ h1, const float* __restrict__ W2,
                          const float* __restrict__ as2, const float* __restrict__ ad2,
                          float* __restrict__ h2pre, float* __restrict__ ssrc2,
                          float* __restrict__ sdst2) {
    __shared__ float sh[128];
    __shared__ float red[128];
    int n = blockIdx.x, t = threadIdx.x;
    sh[t] = h1[n * 128 + t];
    __syncthreads();
    int c = t & 31, q = t >> 5;
    float p = 0.f;
    #pragma unroll
    for (int k = 0; k < 32; k++) p += sh[q * 32 + k] * W2[(q * 32 + k) * 32 + c];
    red[t] = p;
    __syncthreads();
    if (t < 32) {
        float hv = red[t] + red[t + 32] + red[t + 64] + red[t + 96];
        h2pre[n * 32 + t] = hv;
        float a = hv * as2[t], b = hv * ad2[t];
        #pragma unroll
        for (int off = 1; off < 32; off <<= 1) { a += __shfl_xor(a, off); b += __shfl_xor(b, off); }
        if (t == 0) { ssrc2[n] = a; sdst2[n] = b; }
    }
}

// ---------------- layer 2 aggregation (one wave per dst node) ----------------
__global__ void l2_agg(const int* __restrict__ ei, const float* __restrict__ ea,
                       const int* __restrict__ rowoff, const int* __restrict__ eid,
                       const float* __restrict__ ssrc2, const float* __restrict__ sdst2,
                       const float* __restrict__ h2pre, const float* __restrict__ b2,
                       const float* __restrict__ hdr, float* __restrict__ h2) {
    int n = blockIdx.x * 4 + (threadIdx.x >> 6);
    if (n >= N_NODES) return;
    int lane = threadIdx.x & 63;
    int start = rowoff[n], deg = rowoff[n + 1] - start;
    float ea_mean = hdr[0], ce = hdr[5];
    float sd = sdst2[n];

    float m = -1e30f;
    for (int k = lane; k < deg; k += 64) {
        int e = eid[start + k];
        int s = (e < N_EDGES) ? ei[e] : (e - N_EDGES);
        float eav = (e < N_EDGES) ? ea[e] : ea_mean;
        m = fmaxf(m, lrelu(ssrc2[s] + sd + eav * ce));
    }
    #pragma unroll
    for (int off = 1; off < 64; off <<= 1) m = fmaxf(m, __shfl_xor(m, off));

    float den = 0.f;
    for (int k = lane; k < deg; k += 64) {
        int e = eid[start + k];
        int s = (e < N_EDGES) ? ei[e] : (e - N_EDGES);
        float eav = (e < N_EDGES) ? ea[e] : ea_mean;
        den += expf(lrelu(ssrc2[s] + sd + eav * ce) - m);
    }
    #pragma unroll
    for (int off = 1; off < 64; off <<= 1) den += __shfl_xor(den, off);
    float inv = 1.f / (den + 1e-16f);

    // two edges in flight: half-wave 0 takes even j, half-wave 1 odd j
    int c = lane & 31, half = lane >> 5;
    float acc = 0.f;
    for (int j = half; j < deg; j += 2) {
        int e = eid[start + j];
        int s = (e < N_EDGES) ? ei[e] : (e - N_EDGES);
        float eav = (e < N_EDGES) ? ea[e] : ea_mean;
        float alpha = expf(lrelu(ssrc2[s] + sd + eav * ce) - m) * inv;
        acc += alpha * h2pre[s * 32 + c];
    }
    acc += __shfl_xor(acc, 32);
    if (lane < 32) h2[n * 32 + lane] = elu1(acc + b2[lane]);
}

// ---------------- heads: scores (actor) + value accumulation (critic) ----------------
__global__ void scores_value(const float* __restrict__ h2, const float* __restrict__ Wa,
                             const float* __restrict__ ba, const float* __restrict__ Wc,
                             float* __restrict__ scores, float* hdr) {
    int n = blockIdx.x * blockDim.x + threadIdx.x;
    float vc = 0.f;
    if (n < N_NODES) {
        float va = 0.f;
        #pragma unroll
        for (int cidx = 0; cidx < 32; cidx++) {
            float hv = h2[n * 32 + cidx];
            va += hv * Wa[cidx];
            vc += hv * Wc[cidx];
        }
        scores[n] = va + ba[0];
    }
    #pragma unroll
    for (int off = 1; off < 64; off <<= 1) vc += __shfl_xor(vc, off);
    if ((threadIdx.x & 63) == 0) atomicAdd(&hdr[6], vc);
}

// ---------------- portfolio softmax + value write ----------------
__global__ void softmax_w(const float* __restrict__ scores, const int* __restrict__ sidx,
                          const float* __restrict__ cash, const float* __restrict__ hdr,
                          const float* __restrict__ bc, float* __restrict__ out) {
    __shared__ float red[1024];
    int t = threadIdx.x;
    float m = -1e30f;
    for (int i = t; i < NSTK + 1; i += 1024) {
        float v = (i == 0) ? cash[0] : scores[sidx[i - 1]];
        m = fmaxf(m, v);
    }
    red[t] = m;
    __syncthreads();
    for (int s = 512; s > 0; s >>= 1) { if (t < s) red[t] = fmaxf(red[t], red[t + s]); __syncthreads(); }
    m = red[0];
    __syncthreads();
    float sum = 0.f;
    for (int i = t; i < NSTK + 1; i += 1024) {
        float v = (i == 0) ? cash[0] : scores[sidx[i - 1]];
        sum += expf(v - m);
    }
    red[t] = sum;
    __syncthreads();
    for (int s = 512; s > 0; s >>= 1) { if (t < s) red[t] += red[t + s]; __syncthreads(); }
    float inv = 1.f / red[0];
    for (int i = t; i < NSTK + 1; i += 1024) {
        float v = (i == 0) ? cash[0] : scores[sidx[i - 1]];
        out[OUT_W + i] = expf(v - m) * inv;
    }
    if (t == 0) out[OUT_V] = hdr[6] / (float)N_NODES + bc[0];
}

extern "C" void kernel_launch(void* const* d_in, const int* in_sizes, int n_in,
                              void* d_out, int out_size, void* d_ws, size_t ws_size,
                              hipStream_t stream) {
    const float* x    = (const float*)d_in[0];
    const float* ea   = (const float*)d_in[1];
    const float* W1   = (const float*)d_in[2];
    const float* as1  = (const float*)d_in[3];
    const float* ad1  = (const float*)d_in[4];
    const float* We1  = (const float*)d_in[5];
    const float* ae1  = (const float*)d_in[6];
    const float* b1   = (const float*)d_in[7];
    const float* W2   = (const float*)d_in[8];
    const float* as2  = (const float*)d_in[9];
    const float* ad2  = (const float*)d_in[10];
    const float* We2  = (const float*)d_in[11];
    const float* ae2  = (const float*)d_in[12];
    const float* b2   = (const float*)d_in[13];
    const float* Wa   = (const float*)d_in[14];
    const float* ba   = (const float*)d_in[15];
    const float* cash = (const float*)d_in[16];
    const float* Wc   = (const float*)d_in[17];
    const float* bc   = (const float*)d_in[18];
    const int*   ei   = (const int*)d_in[19];
    const int*   sidx = (const int*)d_in[20];

    // workspace layout
    char* w = (char*)d_ws;
    float* hdr    = (float*)w;               // 64 floats
    int*   deg    = (int*)(w + 256);         // N
    int*   cursor = deg + N_NODES;           // N  (contiguous with deg for one memset)
    int*   rowoff = cursor + N_NODES;        // N+1
    int*   eid    = rowoff + N_NODES + 1;    // EF
    float* h1pre  = (float*)(eid + EF);      // N*128
    float* ssrc1  = h1pre + N_NODES * 128;   // N*4
    float* sdst1  = ssrc1 + N_NODES * 4;     // N*4
    float* h1     = sdst1 + N_NODES * 4;     // N*128
    float* h2pre  = h1 + N_NODES * 128;      // N*32
    float* ssrc2  = h2pre + N_NODES * 32;    // N
    float* sdst2  = ssrc2 + N_NODES;         // N
    float* h2     = sdst2 + N_NODES;         // N*32
    float* scores = h2 + N_NODES * 32;       // N

    float* out = (float*)d_out;

    hipMemsetAsync(hdr, 0, 256, stream);
    hipMemsetAsync(deg, 0, 2 * N_NODES * sizeof(int), stream);

    int egrid = (EF + 255) / 256;
    edge_prep<<<2048, 256, 0, stream>>>(ei, ea, deg, out + OUT_EIF, hdr);
    scan_scalar<<<1, SCAN_T, 0, stream>>>(deg, rowoff, We1, ae1, We2, ae2, hdr);
    fill_csr<<<egrid, 256, 0, stream>>>(ei, rowoff, cursor, eid);

    node_lin1<<<N_NODES, 128, 0, stream>>>(x, W1, as1, ad1, h1pre, ssrc1, sdst1);
    l1_agg<<<(N_NODES + 3) / 4, 256, 0, stream>>>(ei, ea, rowoff, eid, ssrc1, sdst1, h1pre,
                                                  b1, hdr, out + OUT_A1, h1);
    node_lin2<<<N_NODES, 128, 0, stream>>>(h1, W2, as2, ad2, h2pre, ssrc2, sdst2);
    l2_agg<<<(N_NODES + 3) / 4, 256, 0, stream>>>(ei, ea, rowoff, eid, ssrc2, sdst2, h2pre,
                                                  b2, hdr, h2);
    scores_value<<<(N_NODES + 255) / 256, 256, 0, stream>>>(h2, Wa, ba, Wc, scores, hdr);
    softmax_w<<<1, 1024, 0, stream>>>(scores, sidx, cash, hdr, bc, out);
}

// Round 5
// 946.343 us; speedup vs baseline: 1.1767x; 1.1767x over previous
//
#include <hip/hip_runtime.h>
#include <hip/hip_fp16.h>
#include <math.h>

#define N_NODES 50000
#define N_EDGES 1600000
#define EF      (N_EDGES + N_NODES)
#define NSTK    25000
#define IN_DIM  5
#define HID     32
#define HEADS   4
#define NEG_SLOPE 0.2f

#define SCAN_T  1024
#define CHUNK   ((N_NODES + SCAN_T - 1) / SCAN_T)   // 49

// d_out layout (floats): weights[25001] | value[1] | edge_index_full[2*EF] | alpha1[EF*4]
#define OUT_W   0
#define OUT_V   (NSTK + 1)
#define OUT_EIF (NSTK + 2)
#define OUT_A1  (OUT_EIF + 2 * EF)

__device__ __forceinline__ float lrelu(float x) { return x > 0.f ? x : NEG_SLOPE * x; }
__device__ __forceinline__ float elu1(float x)  { return x > 0.f ? x : expf(x) - 1.f; }

// ---------------- fused edge prep ----------------
// One pass over the edge list: dst-degree atomics, ea partial sum, edge_index_full out.
// hdr[0]=ea sum (finalized to mean in scan_scalar), hdr[1..4]=ce1[h], hdr[5]=ce2, hdr[6]=value
__global__ void edge_prep(const int* __restrict__ ei, const float* __restrict__ ea,
                          int* __restrict__ deg, float* __restrict__ out_eif, float* hdr) {
    float s = 0.f;
    for (int e = blockIdx.x * blockDim.x + threadIdx.x; e < EF; e += gridDim.x * blockDim.x) {
        int sv, dv;
        if (e < N_EDGES) {
            sv = ei[e];
            dv = ei[N_EDGES + e];
            s += ea[e];
        } else {
            sv = dv = e - N_EDGES;
        }
        atomicAdd(&deg[dv], 1);
        out_eif[e]      = (float)sv;
        out_eif[EF + e] = (float)dv;
    }
    #pragma unroll
    for (int off = 1; off < 64; off <<= 1) s += __shfl_xor(s, off);
    if ((threadIdx.x & 63) == 0) atomicAdd(&hdr[0], s);
}

// ---------------- scan (serial-chunk) + scalar prep ----------------
__global__ void scan_scalar(const int* __restrict__ deg, int* __restrict__ rowoff,
                            const float* __restrict__ We1, const float* __restrict__ ae1,
                            const float* __restrict__ We2, const float* __restrict__ ae2,
                            float* hdr) {
    __shared__ int sums[SCAN_T];
    int t = threadIdx.x;

    if (t < 128) {
        float p = We1[t] * ae1[t];
        #pragma unroll
        for (int off = 1; off < 32; off <<= 1) p += __shfl_xor(p, off);
        if ((t & 31) == 0) hdr[1 + (t >> 5)] = p;
        if (t < 32) {
            float q = We2[t] * ae2[t];
            #pragma unroll
            for (int off = 1; off < 32; off <<= 1) q += __shfl_xor(q, off);
            if (t == 0) { hdr[5] = q; hdr[0] = hdr[0] / (float)N_EDGES; }
        }
    }

    int base = t * CHUNK;
    int local = 0;
    for (int i = 0; i < CHUNK; i++) {
        int idx = base + i;
        if (idx < N_NODES) local += deg[idx];
    }
    sums[t] = local;
    __syncthreads();
    #pragma unroll
    for (int off = 1; off < SCAN_T; off <<= 1) {
        int v = (t >= off) ? sums[t - off] : 0;
        __syncthreads();
        sums[t] += v;
        __syncthreads();
    }
    int run = sums[t] - local;          // exclusive prefix of this chunk
    if (t == 0) rowoff[0] = 0;
    for (int i = 0; i < CHUNK; i++) {
        int idx = base + i;
        if (idx < N_NODES) { run += deg[idx]; rowoff[idx + 1] = run; }
    }
}

// ---------------- CSR fill: also materialize src and edge-attr values ----------------
// Hot loops then never gather ei[e]/ea[e] randomly.
__global__ void fill_csr(const int* __restrict__ ei, const float* __restrict__ ea,
                         const int* __restrict__ rowoff, const float* __restrict__ hdr,
                         int* cursor, int* __restrict__ eid, int* __restrict__ esrc,
                         float* __restrict__ eaval) {
    float ea_mean = hdr[0];
    for (int e = blockIdx.x * blockDim.x + threadIdx.x; e < EF; e += gridDim.x * blockDim.x) {
        int s, d; float av;
        if (e < N_EDGES) { s = ei[e]; d = ei[N_EDGES + e]; av = ea[e]; }
        else             { s = d = e - N_EDGES;            av = ea_mean; }
        int pos = rowoff[d] + atomicAdd(&cursor[d], 1);
        eid[pos]   = e;
        esrc[pos]  = s;
        eaval[pos] = av;
    }
}

// ---------------- layer 1 linear + attention scalars ----------------
// h1pre stored fp16 (halves the l1_agg gather traffic); ssrc/sdst from fp32 value.
__global__ void node_lin1(const float* __restrict__ x, const float* __restrict__ W1,
                          const float* __restrict__ as1, const float* __restrict__ ad1,
                          __half* __restrict__ h1pre, float* __restrict__ ssrc1,
                          float* __restrict__ sdst1) {
    int n = blockIdx.x, t = threadIdx.x;
    float hv = 0.f;
    #pragma unroll
    for (int k = 0; k < IN_DIM; k++) hv += x[n * IN_DIM + k] * W1[k * 128 + t];
    h1pre[n * 128 + t] = __float2half(hv);
    float a = hv * as1[t];
    float b = hv * ad1[t];
    #pragma unroll
    for (int off = 1; off < 32; off <<= 1) { a += __shfl_xor(a, off); b += __shfl_xor(b, off); }
    if ((t & 31) == 0) { ssrc1[n * 4 + (t >> 5)] = a; sdst1[n * 4 + (t >> 5)] = b; }
}

// ---------------- layer 1 aggregation (one wave per dst node) ----------------
// Lane l owns channels {2l, 2l+1} -> single head h = l>>4 -> one exp per edge.
// Alpha written exactly once (from the acc loop), two float2 stores by lane 0.
__global__ void l1_agg(const int* __restrict__ eid, const int* __restrict__ esrc,
                       const float* __restrict__ eaval, const int* __restrict__ rowoff,
                       const float* __restrict__ ssrc1, const float* __restrict__ sdst1,
                       const __half2* __restrict__ h1pre, const float* __restrict__ b1,
                       const float* __restrict__ hdr, float* __restrict__ alpha_out,
                       float* __restrict__ h1) {
    int n = blockIdx.x * 4 + (threadIdx.x >> 6);
    if (n >= N_NODES) return;
    int lane = threadIdx.x & 63;
    int start = rowoff[n], deg = rowoff[n + 1] - start;
    int hl = lane & 3;
    float ce = hdr[1 + hl];
    float sd = sdst1[n * 4 + hl];

    float m = -1e30f;
    for (int k = lane; k < deg * 4; k += 64) {
        int p = start + (k >> 2);
        float lg = ssrc1[esrc[p] * 4 + hl] + sd + eaval[p] * ce;
        m = fmaxf(m, lrelu(lg));
    }
    #pragma unroll
    for (int off = 4; off < 64; off <<= 1) m = fmaxf(m, __shfl_xor(m, off));

    float den = 0.f;
    for (int k = lane; k < deg * 4; k += 64) {
        int p = start + (k >> 2);
        float lg = ssrc1[esrc[p] * 4 + hl] + sd + eaval[p] * ce;
        den += expf(lrelu(lg) - m);
    }
    #pragma unroll
    for (int off = 4; off < 64; off <<= 1) den += __shfl_xor(den, off);
    float inv = 1.f / (den + 1e-16f);

    // accumulation; head params for this lane's channel pair live on lane h (<4)
    int h = lane >> 4;
    float mh  = __shfl(m, h),  invh = __shfl(inv, h);
    float sdh = __shfl(sd, h), ceh  = __shfl(ce, h);
    float acc0 = 0.f, acc1 = 0.f;
    for (int j = 0; j < deg; j++) {
        int p = start + j;
        int s = esrc[p];
        float a = expf(lrelu(ssrc1[s * 4 + h] + sdh + eaval[p] * ceh) - mh) * invh;
        float2 f = __half22float2(h1pre[s * 64 + lane]);
        acc0 += a * f.x;
        acc1 += a * f.y;
        float a0 = __shfl(a, 0),  a1 = __shfl(a, 16);
        float a2 = __shfl(a, 32), a3 = __shfl(a, 48);
        if (lane == 0) {
            int e = eid[p];
            float2* ap = (float2*)(alpha_out + (size_t)e * 4);
            ap[0] = make_float2(a0, a1);
            ap[1] = make_float2(a2, a3);
        }
    }
    int c0 = lane * 2;
    float2 bb = *(const float2*)(b1 + c0);
    *(float2*)(h1 + n * 128 + c0) = make_float2(elu1(acc0 + bb.x), elu1(acc1 + bb.y));
}

// ---------------- layer 2 linear + attention scalars ----------------
__global__ void node_lin2(const float* __restrict__ h1, const float* __restrict__ W2,
                          const float* __restrict__ as2, const float* __restrict__ ad2,
                          float* __restrict__ h2pre, float* __restrict__ ssrc2,
                          float* __restrict__ sdst2) {
    __shared__ float sh[128];
    __shared__ float red[128];
    int n = blockIdx.x, t = threadIdx.x;
    sh[t] = h1[n * 128 + t];
    __syncthreads();
    int c = t & 31, q = t >> 5;
    float p = 0.f;
    #pragma unroll
    for (int k = 0; k < 32; k++) p += sh[q * 32 + k] * W2[(q * 32 + k) * 32 + c];
    red[t] = p;
    __syncthreads();
    if (t < 32) {
        float hv = red[t] + red[t + 32] + red[t + 64] + red[t + 96];
        h2pre[n * 32 + t] = hv;
        float a = hv * as2[t], b = hv * ad2[t];
        #pragma unroll
        for (int off = 1; off < 32; off <<= 1) { a += __shfl_xor(a, off); b += __shfl_xor(b, off); }
        if (t == 0) { ssrc2[n] = a; sdst2[n] = b; }
    }
}

// ---------------- layer 2 aggregation (one wave per dst node) ----------------
__global__ void l2_agg(const int* __restrict__ esrc, const float* __restrict__ eaval,
                       const int* __restrict__ rowoff, const float* __restrict__ ssrc2,
                       const float* __restrict__ sdst2, const float* __restrict__ h2pre,
                       const float* __restrict__ b2, const float* __restrict__ hdr,
                       float* __restrict__ h2) {
    int n = blockIdx.x * 4 + (threadIdx.x >> 6);
    if (n >= N_NODES) return;
    int lane = threadIdx.x & 63;
    int start = rowoff[n], deg = rowoff[n + 1] - start;
    float ce = hdr[5];
    float sd = sdst2[n];

    float m = -1e30f;
    for (int k = lane; k < deg; k += 64) {
        int p = start + k;
        m = fmaxf(m, lrelu(ssrc2[esrc[p]] + sd + eaval[p] * ce));
    }
    #pragma unroll
    for (int off = 1; off < 64; off <<= 1) m = fmaxf(m, __shfl_xor(m, off));

    float den = 0.f;
    for (int k = lane; k < deg; k += 64) {
        int p = start + k;
        den += expf(lrelu(ssrc2[esrc[p]] + sd + eaval[p] * ce) - m);
    }
    #pragma unroll
    for (int off = 1; off < 64; off <<= 1) den += __shfl_xor(den, off);
    float inv = 1.f / (den + 1e-16f);

    // two edges in flight: half-wave 0 takes even j, half-wave 1 odd j
    int c = lane & 31, half = lane >> 5;
    float acc = 0.f;
    for (int j = half; j < deg; j += 2) {
        int p = start + j;
        int s = esrc[p];
        float alpha = expf(lrelu(ssrc2[s] + sd + eaval[p] * ce) - m) * inv;
        acc += alpha * h2pre[s * 32 + c];
    }
    acc += __shfl_xor(acc, 32);
    if (lane < 32) h2[n * 32 + lane] = elu1(acc + b2[lane]);
}

// ---------------- heads: scores (actor) + value accumulation (critic) ----------------
__global__ void scores_value(const float* __restrict__ h2, const float* __restrict__ Wa,
                             const float* __restrict__ ba, const float* __restrict__ Wc,
                             float* __restrict__ scores, float* hdr) {
    int n = blockIdx.x * blockDim.x + threadIdx.x;
    float vc = 0.f;
    if (n < N_NODES) {
        float va = 0.f;
        #pragma unroll
        for (int cidx = 0; cidx < 32; cidx++) {
            float hv = h2[n * 32 + cidx];
            va += hv * Wa[cidx];
            vc += hv * Wc[cidx];
        }
        scores[n] = va + ba[0];
    }
    #pragma unroll
    for (int off = 1; off < 64; off <<= 1) vc += __shfl_xor(vc, off);
    if ((threadIdx.x & 63) == 0) atomicAdd(&hdr[6], vc);
}

// ---------------- portfolio softmax + value write ----------------
__global__ void softmax_w(const float* __restrict__ scores, const int* __restrict__ sidx,
                          const float* __restrict__ cash, const float* __restrict__ hdr,
                          const float* __restrict__ bc, float* __restrict__ out) {
    __shared__ float red[1024];
    int t = threadIdx.x;
    float m = -1e30f;
    for (int i = t; i < NSTK + 1; i += 1024) {
        float v = (i == 0) ? cash[0] : scores[sidx[i - 1]];
        m = fmaxf(m, v);
    }
    red[t] = m;
    __syncthreads();
    for (int s = 512; s > 0; s >>= 1) { if (t < s) red[t] = fmaxf(red[t], red[t + s]); __syncthreads(); }
    m = red[0];
    __syncthreads();
    float sum = 0.f;
    for (int i = t; i < NSTK + 1; i += 1024) {
        float v = (i == 0) ? cash[0] : scores[sidx[i - 1]];
        sum += expf(v - m);
    }
    red[t] = sum;
    __syncthreads();
    for (int s = 512; s > 0; s >>= 1) { if (t < s) red[t] += red[t + s]; __syncthreads(); }
    float inv = 1.f / red[0];
    for (int i = t; i < NSTK + 1; i += 1024) {
        float v = (i == 0) ? cash[0] : scores[sidx[i - 1]];
        out[OUT_W + i] = expf(v - m) * inv;
    }
    if (t == 0) out[OUT_V] = hdr[6] / (float)N_NODES + bc[0];
}

extern "C" void kernel_launch(void* const* d_in, const int* in_sizes, int n_in,
                              void* d_out, int out_size, void* d_ws, size_t ws_size,
                              hipStream_t stream) {
    const float* x    = (const float*)d_in[0];
    const float* ea   = (const float*)d_in[1];
    const float* W1   = (const float*)d_in[2];
    const float* as1  = (const float*)d_in[3];
    const float* ad1  = (const float*)d_in[4];
    const float* We1  = (const float*)d_in[5];
    const float* ae1  = (const float*)d_in[6];
    const float* b1   = (const float*)d_in[7];
    const float* W2   = (const float*)d_in[8];
    const float* as2  = (const float*)d_in[9];
    const float* ad2  = (const float*)d_in[10];
    const float* We2  = (const float*)d_in[11];
    const float* ae2  = (const float*)d_in[12];
    const float* b2   = (const float*)d_in[13];
    const float* Wa   = (const float*)d_in[14];
    const float* ba   = (const float*)d_in[15];
    const float* cash = (const float*)d_in[16];
    const float* Wc   = (const float*)d_in[17];
    const float* bc   = (const float*)d_in[18];
    const int*   ei   = (const int*)d_in[19];
    const int*   sidx = (const int*)d_in[20];

    // workspace layout — every array a multiple of 4 elements so all bases stay 16B-aligned
    char* w = (char*)d_ws;
    float* hdr    = (float*)w;                  // 64 floats
    int*   deg    = (int*)(w + 256);            // N
    int*   cursor = deg + N_NODES;              // N (contiguous with deg -> one memset)
    int*   rowoff = cursor + N_NODES;           // N+4 (padded)
    int*   eid    = rowoff + N_NODES + 4;       // EF
    int*   esrc   = eid + EF;                   // EF
    float* eaval  = (float*)(esrc + EF);        // EF
    __half* h1pre = (__half*)(eaval + EF);      // N*128 halfs = N*64 floats
    float* ssrc1  = (float*)(eaval + EF) + N_NODES * 64;  // N*4
    float* sdst1  = ssrc1 + N_NODES * 4;        // N*4
    float* h1     = sdst1 + N_NODES * 4;        // N*128
    float* h2pre  = h1 + N_NODES * 128;         // N*32
    float* ssrc2  = h2pre + N_NODES * 32;       // N
    float* sdst2  = ssrc2 + N_NODES;            // N
    float* h2     = sdst2 + N_NODES;            // N*32
    float* scores = h2 + N_NODES * 32;          // N

    float* out = (float*)d_out;

    hipMemsetAsync(hdr, 0, 256, stream);
    hipMemsetAsync(deg, 0, 2 * N_NODES * sizeof(int), stream);

    int egrid = (EF + 255) / 256;
    edge_prep<<<2048, 256, 0, stream>>>(ei, ea, deg, out + OUT_EIF, hdr);
    scan_scalar<<<1, SCAN_T, 0, stream>>>(deg, rowoff, We1, ae1, We2, ae2, hdr);
    fill_csr<<<egrid, 256, 0, stream>>>(ei, ea, rowoff, hdr, cursor, eid, esrc, eaval);

    node_lin1<<<N_NODES, 128, 0, stream>>>(x, W1, as1, ad1, h1pre, ssrc1, sdst1);
    l1_agg<<<(N_NODES + 3) / 4, 256, 0, stream>>>(eid, esrc, eaval, rowoff, ssrc1, sdst1,
                                                  (const __half2*)h1pre, b1, hdr,
                                                  out + OUT_A1, h1);
    node_lin2<<<N_NODES, 128, 0, stream>>>(h1, W2, as2, ad2, h2pre, ssrc2, sdst2);
    l2_agg<<<(N_NODES + 3) / 4, 256, 0, stream>>>(esrc, eaval, rowoff, ssrc2, sdst2, h2pre,
                                                  b2, hdr, h2);
    scores_value<<<(N_NODES + 255) / 256, 256, 0, stream>>>(h2, Wa, ba, Wc, scores, hdr);
    softmax_w<<<1, 1024, 0, stream>>>(scores, sidx, cash, hdr, bc, out);
}

// Round 6
// 716.083 us; speedup vs baseline: 1.5551x; 1.3216x over previous
//
#include <hip/hip_runtime.h>
#include <hip/hip_fp16.h>
#include <math.h>

#define N_NODES 50000
#define N_EDGES 1600000
#define EF      (N_EDGES + N_NODES)
#define NSTK    25000
#define IN_DIM  5
#define HID     32
#define HEADS   4
#define NEG_SLOPE 0.2f

#define SCAN_T  1024
#define CHUNK   ((N_NODES + SCAN_T - 1) / SCAN_T)   // 49
#define JMAX    128                                  // LDS p-cache slots per node (deg>128 is ~never)

// d_out layout (floats): weights[25001] | value[1] | edge_index_full[2*EF] | alpha1[EF*4]
#define OUT_W   0
#define OUT_V   (NSTK + 1)
#define OUT_EIF (NSTK + 2)
#define OUT_A1  (OUT_EIF + 2 * EF)

struct alignas(8) EPack { int s; float av; };        // CSR payload: src node + edge attr

__device__ __forceinline__ float lrelu(float x) { return x > 0.f ? x : NEG_SLOPE * x; }
__device__ __forceinline__ float elu1(float x)  { return x > 0.f ? x : expf(x) - 1.f; }

// ---------------- fused edge prep ----------------
// hdr[0]=ea sum (finalized to mean in scan_scalar), hdr[1..4]=ce1[h], hdr[5]=ce2, hdr[6]=value
__global__ void edge_prep(const int* __restrict__ ei, const float* __restrict__ ea,
                          int* __restrict__ deg, float* __restrict__ out_eif, float* hdr) {
    float s = 0.f;
    for (int e = blockIdx.x * blockDim.x + threadIdx.x; e < EF; e += gridDim.x * blockDim.x) {
        int sv, dv;
        if (e < N_EDGES) {
            sv = ei[e];
            dv = ei[N_EDGES + e];
            s += ea[e];
        } else {
            sv = dv = e - N_EDGES;
        }
        atomicAdd(&deg[dv], 1);
        out_eif[e]      = (float)sv;
        out_eif[EF + e] = (float)dv;
    }
    #pragma unroll
    for (int off = 1; off < 64; off <<= 1) s += __shfl_xor(s, off);
    if ((threadIdx.x & 63) == 0) atomicAdd(&hdr[0], s);
}

// ---------------- scan (serial-chunk) + scalar prep ----------------
__global__ void scan_scalar(const int* __restrict__ deg, int* __restrict__ rowoff,
                            const float* __restrict__ We1, const float* __restrict__ ae1,
                            const float* __restrict__ We2, const float* __restrict__ ae2,
                            float* hdr) {
    __shared__ int sums[SCAN_T];
    int t = threadIdx.x;

    if (t < 128) {
        float p = We1[t] * ae1[t];
        #pragma unroll
        for (int off = 1; off < 32; off <<= 1) p += __shfl_xor(p, off);
        if ((t & 31) == 0) hdr[1 + (t >> 5)] = p;
        if (t < 32) {
            float q = We2[t] * ae2[t];
            #pragma unroll
            for (int off = 1; off < 32; off <<= 1) q += __shfl_xor(q, off);
            if (t == 0) { hdr[5] = q; hdr[0] = hdr[0] / (float)N_EDGES; }
        }
    }

    int base = t * CHUNK;
    int local = 0;
    for (int i = 0; i < CHUNK; i++) {
        int idx = base + i;
        if (idx < N_NODES) local += deg[idx];
    }
    sums[t] = local;
    __syncthreads();
    #pragma unroll
    for (int off = 1; off < SCAN_T; off <<= 1) {
        int v = (t >= off) ? sums[t - off] : 0;
        __syncthreads();
        sums[t] += v;
        __syncthreads();
    }
    int run = sums[t] - local;          // exclusive prefix of this chunk
    if (t == 0) rowoff[0] = 0;
    for (int i = 0; i < CHUNK; i++) {
        int idx = base + i;
        if (idx < N_NODES) { run += deg[idx]; rowoff[idx + 1] = run; }
    }
}

// ---------------- CSR fill: single 8B payload store per edge ----------------
__global__ void fill_csr(const int* __restrict__ ei, const float* __restrict__ ea,
                         const int* __restrict__ rowoff, const float* __restrict__ hdr,
                         int* cursor, EPack* __restrict__ epack) {
    float ea_mean = hdr[0];
    for (int e = blockIdx.x * blockDim.x + threadIdx.x; e < EF; e += gridDim.x * blockDim.x) {
        int s, d; float av;
        if (e < N_EDGES) { s = ei[e]; d = ei[N_EDGES + e]; av = ea[e]; }
        else             { s = d = e - N_EDGES;            av = ea_mean; }
        int pos = rowoff[d] + atomicAdd(&cursor[d], 1);
        EPack ep; ep.s = s; ep.av = av;
        epack[pos] = ep;
    }
}

// ---------------- layer 1 linear + attention scalars ----------------
__global__ void node_lin1(const float* __restrict__ x, const float* __restrict__ W1,
                          const float* __restrict__ as1, const float* __restrict__ ad1,
                          __half* __restrict__ h1pre, float* __restrict__ ssrc1,
                          float* __restrict__ sdst1) {
    int n = blockIdx.x, t = threadIdx.x;
    float hv = 0.f;
    #pragma unroll
    for (int k = 0; k < IN_DIM; k++) hv += x[n * IN_DIM + k] * W1[k * 128 + t];
    h1pre[n * 128 + t] = __float2half(hv);
    float a = hv * as1[t];
    float b = hv * ad1[t];
    #pragma unroll
    for (int off = 1; off < 32; off <<= 1) { a += __shfl_xor(a, off); b += __shfl_xor(b, off); }
    if ((t & 31) == 0) { ssrc1[n * 4 + (t >> 5)] = a; sdst1[n * 4 + (t >> 5)] = b; }
}

// ---------------- layer 1 aggregation: one wave per dst node ----------------
// pass1: m.  pass2: p=exp(...) -> LDS + den.  pass3: acc, 4 edges/iter,
// 16 lanes/edge, 8 fp16 channels/lane via one 16B gather. No exp/shfl in acc.
__global__ void l1_agg(const EPack* __restrict__ epack, const int* __restrict__ rowoff,
                       const float* __restrict__ ssrc1, const float* __restrict__ sdst1,
                       const __half* __restrict__ h1pre, const float* __restrict__ b1,
                       const float* __restrict__ hdr, float* __restrict__ minv,
                       float* __restrict__ h1) {
    __shared__ float lds_p[4][HEADS][JMAX + 4];
    int wid = threadIdx.x >> 6;
    int n = blockIdx.x * 4 + wid;
    if (n >= N_NODES) return;
    int lane = threadIdx.x & 63;
    int start = rowoff[n], deg = rowoff[n + 1] - start;
    int hl = lane & 3;
    float ce = hdr[1 + hl];
    float sd = sdst1[n * 4 + hl];

    float m = -1e30f;
    for (int k = lane; k < deg * 4; k += 64) {
        EPack ep = epack[start + (k >> 2)];
        m = fmaxf(m, lrelu(ssrc1[ep.s * 4 + hl] + sd + ep.av * ce));
    }
    #pragma unroll
    for (int off = 4; off < 64; off <<= 1) m = fmaxf(m, __shfl_xor(m, off));

    float den = 0.f;
    for (int k = lane; k < deg * 4; k += 64) {
        int j = k >> 2;
        EPack ep = epack[start + j];
        float pv = expf(lrelu(ssrc1[ep.s * 4 + hl] + sd + ep.av * ce) - m);
        den += pv;
        if (j < JMAX) lds_p[wid][hl][j] = pv;
    }
    #pragma unroll
    for (int off = 4; off < 64; off <<= 1) den += __shfl_xor(den, off);
    float inv = 1.f / (den + 1e-16f);

    // publish m/inv per head for the alpha_write kernel
    {
        float mh = __shfl(m,  lane & 3);
        float ih = __shfl(inv, lane & 3);
        if (lane < 8) minv[n * 8 + lane] = (lane < 4) ? mh : ih;
    }

    __builtin_amdgcn_wave_barrier();   // order LDS p writes before acc reads (no cross-wave dep)

    int sub = lane & 15, el = lane >> 4;
    int h = sub >> 2;                  // this lane's head (channels sub*8..sub*8+7)
    float invh = __shfl(inv, h);
    int jcap = deg < JMAX ? deg : JMAX;
    float acc[8];
    #pragma unroll
    for (int i = 0; i < 8; i++) acc[i] = 0.f;

    for (int j0 = 0; j0 < jcap; j0 += 4) {
        int j = j0 + el;
        float a = 0.f; int s = 0;
        if (j < jcap) { a = lds_p[wid][h][j] * invh; s = epack[start + j].s; }
        const uint4 rv = *(const uint4*)(h1pre + (size_t)s * 128 + sub * 8);
        const __half2* hp = (const __half2*)&rv;
        #pragma unroll
        for (int i = 0; i < 4; i++) {
            float2 f = __half22float2(hp[i]);
            acc[2 * i]     += a * f.x;
            acc[2 * i + 1] += a * f.y;
        }
    }
    if (deg > JMAX) {                  // rare fallback: recompute alpha
        float mh = __shfl(m, h), sdh = __shfl(sd, h), ceh = __shfl(ce, h);
        for (int j0 = JMAX; j0 < deg; j0 += 4) {
            int j = j0 + el;
            float a = 0.f; int s = 0;
            if (j < deg) {
                EPack ep = epack[start + j];
                s = ep.s;
                a = expf(lrelu(ssrc1[s * 4 + h] + sdh + ep.av * ceh) - mh) * invh;
            }
            const uint4 rv = *(const uint4*)(h1pre + (size_t)s * 128 + sub * 8);
            const __half2* hp = (const __half2*)&rv;
            #pragma unroll
            for (int i = 0; i < 4; i++) {
                float2 f = __half22float2(hp[i]);
                acc[2 * i]     += a * f.x;
                acc[2 * i + 1] += a * f.y;
            }
        }
    }

    #pragma unroll
    for (int i = 0; i < 8; i++) {
        acc[i] += __shfl_xor(acc[i], 16);
        acc[i] += __shfl_xor(acc[i], 32);
    }
    if (lane < 16) {
        int c0 = lane * 8;
        float4 bb0 = *(const float4*)(b1 + c0);
        float4 bb1 = *(const float4*)(b1 + c0 + 4);
        float4 r0 = make_float4(elu1(acc[0] + bb0.x), elu1(acc[1] + bb0.y),
                                elu1(acc[2] + bb0.z), elu1(acc[3] + bb0.w));
        float4 r1 = make_float4(elu1(acc[4] + bb1.x), elu1(acc[5] + bb1.y),
                                elu1(acc[6] + bb1.z), elu1(acc[7] + bb1.w));
        *(float4*)(h1 + n * 128 + c0)     = r0;
        *(float4*)(h1 + n * 128 + c0 + 4) = r1;
    }
}

// ---------------- alpha1 output: edge-parallel, original order -> sequential writes ----------------
__global__ void alpha_write(const int* __restrict__ ei, const float* __restrict__ ea,
                            const float* __restrict__ ssrc1, const float* __restrict__ sdst1,
                            const float* __restrict__ minv, const float* __restrict__ hdr,
                            float* __restrict__ alpha_out) {
    float ea_mean = hdr[0];
    float ce0 = hdr[1], ce1 = hdr[2], ce2 = hdr[3], ce3 = hdr[4];
    for (int e = blockIdx.x * blockDim.x + threadIdx.x; e < EF; e += gridDim.x * blockDim.x) {
        int s, d; float av;
        if (e < N_EDGES) { s = ei[e]; d = ei[N_EDGES + e]; av = ea[e]; }
        else             { s = d = e - N_EDGES;            av = ea_mean; }
        float4 ss = *(const float4*)(ssrc1 + (size_t)s * 4);
        float4 dd = *(const float4*)(sdst1 + (size_t)d * 4);
        float4 mm = *(const float4*)(minv + (size_t)d * 8);
        float4 iv = *(const float4*)(minv + (size_t)d * 8 + 4);
        float a0 = expf(lrelu(ss.x + dd.x + av * ce0) - mm.x) * iv.x;
        float a1 = expf(lrelu(ss.y + dd.y + av * ce1) - mm.y) * iv.y;
        float a2 = expf(lrelu(ss.z + dd.z + av * ce2) - mm.z) * iv.z;
        float a3 = expf(lrelu(ss.w + dd.w + av * ce3) - mm.w) * iv.w;
        float2* ap = (float2*)(alpha_out + (size_t)e * 4);
        ap[0] = make_float2(a0, a1);
        ap[1] = make_float2(a2, a3);
    }
}

// ---------------- layer 2 linear + attention scalars ----------------
__global__ void node_lin2(const float* __restrict__ h1, const float* __restrict__ W2,
                          const float* __restrict__ as2, const float* __restrict__ ad2,
                          float* __restrict__ h2pre, float* __restrict__ ssrc2,
                          float* __restrict__ sdst2) {
    __shared__ float sh[128];
    __shared__ float red[128];
    int n = blockIdx.x, t = threadIdx.x;
    sh[t] = h1[n * 128 + t];
    __syncthreads();
    int c = t & 31, q = t >> 5;
    float p = 0.f;
    #pragma unroll
    for (int k = 0; k < 32; k++) p += sh[q * 32 + k] * W2[(q * 32 + k) * 32 + c];
    red[t] = p;
    __syncthreads();
    if (t < 32) {
        float hv = red[t] + red[t + 32] + red[t + 64] + red[t + 96];
        h2pre[n * 32 + t] = hv;
        float a = hv * as2[t], b = hv * ad2[t];
        #pragma unroll
        for (int off = 1; off < 32; off <<= 1) { a += __shfl_xor(a, off); b += __shfl_xor(b, off); }
        if (t == 0) { ssrc2[n] = a; sdst2[n] = b; }
    }
}

// ---------------- layer 2 aggregation: same LDS-p + 4-edge-ILP structure ----------------
__global__ void l2_agg(const EPack* __restrict__ epack, const int* __restrict__ rowoff,
                       const float* __restrict__ ssrc2, const float* __restrict__ sdst2,
                       const float* __restrict__ h2pre, const float* __restrict__ b2,
                       const float* __restrict__ hdr, float* __restrict__ h2) {
    __shared__ float lds_q[4][JMAX + 4];
    int wid = threadIdx.x >> 6;
    int n = blockIdx.x * 4 + wid;
    if (n >= N_NODES) return;
    int lane = threadIdx.x & 63;
    int start = rowoff[n], deg = rowoff[n + 1] - start;
    float ce = hdr[5];
    float sd = sdst2[n];

    float m = -1e30f;
    for (int k = lane; k < deg; k += 64) {
        EPack ep = epack[start + k];
        m = fmaxf(m, lrelu(ssrc2[ep.s] + sd + ep.av * ce));
    }
    #pragma unroll
    for (int off = 1; off < 64; off <<= 1) m = fmaxf(m, __shfl_xor(m, off));

    float den = 0.f;
    for (int k = lane; k < deg; k += 64) {
        EPack ep = epack[start + k];
        float pv = expf(lrelu(ssrc2[ep.s] + sd + ep.av * ce) - m);
        den += pv;
        if (k < JMAX) lds_q[wid][k] = pv;
    }
    #pragma unroll
    for (int off = 1; off < 64; off <<= 1) den += __shfl_xor(den, off);
    float inv = 1.f / (den + 1e-16f);

    __builtin_amdgcn_wave_barrier();

    int sub = lane & 15, el = lane >> 4;   // edge slot el, channel pair sub*2
    int jcap = deg < JMAX ? deg : JMAX;
    float acc0 = 0.f, acc1 = 0.f;
    for (int j0 = 0; j0 < jcap; j0 += 4) {
        int j = j0 + el;
        float a = 0.f; int s = 0;
        if (j < jcap) { a = lds_q[wid][j] * inv; s = epack[start + j].s; }
        float2 f = *(const float2*)(h2pre + (size_t)s * 32 + sub * 2);
        acc0 += a * f.x;
        acc1 += a * f.y;
    }
    if (deg > JMAX) {
        for (int j0 = JMAX; j0 < deg; j0 += 4) {
            int j = j0 + el;
            float a = 0.f; int s = 0;
            if (j < deg) {
                EPack ep = epack[start + j];
                s = ep.s;
                a = expf(lrelu(ssrc2[s] + sd + ep.av * ce) - m) * inv;
            }
            float2 f = *(const float2*)(h2pre + (size_t)s * 32 + sub * 2);
            acc0 += a * f.x;
            acc1 += a * f.y;
        }
    }
    acc0 += __shfl_xor(acc0, 16); acc0 += __shfl_xor(acc0, 32);
    acc1 += __shfl_xor(acc1, 16); acc1 += __shfl_xor(acc1, 32);
    if (lane < 16) {
        float2 bb = *(const float2*)(b2 + lane * 2);
        *(float2*)(h2 + n * 32 + lane * 2) =
            make_float2(elu1(acc0 + bb.x), elu1(acc1 + bb.y));
    }
}

// ---------------- heads: scores (actor) + value accumulation (critic) ----------------
__global__ void scores_value(const float* __restrict__ h2, const float* __restrict__ Wa,
                             const float* __restrict__ ba, const float* __restrict__ Wc,
                             float* __restrict__ scores, float* hdr) {
    int n = blockIdx.x * blockDim.x + threadIdx.x;
    float vc = 0.f;
    if (n < N_NODES) {
        float va = 0.f;
        #pragma unroll
        for (int cidx = 0; cidx < 32; cidx++) {
            float hv = h2[n * 32 + cidx];
            va += hv * Wa[cidx];
            vc += hv * Wc[cidx];
        }
        scores[n] = va + ba[0];
    }
    #pragma unroll
    for (int off = 1; off < 64; off <<= 1) vc += __shfl_xor(vc, off);
    if ((threadIdx.x & 63) == 0) atomicAdd(&hdr[6], vc);
}

// ---------------- portfolio softmax + value write ----------------
__global__ void softmax_w(const float* __restrict__ scores, const int* __restrict__ sidx,
                          const float* __restrict__ cash, const float* __restrict__ hdr,
                          const float* __restrict__ bc, float* __restrict__ out) {
    __shared__ float red[1024];
    int t = threadIdx.x;
    float m = -1e30f;
    for (int i = t; i < NSTK + 1; i += 1024) {
        float v = (i == 0) ? cash[0] : scores[sidx[i - 1]];
        m = fmaxf(m, v);
    }
    red[t] = m;
    __syncthreads();
    for (int s = 512; s > 0; s >>= 1) { if (t < s) red[t] = fmaxf(red[t], red[t + s]); __syncthreads(); }
    m = red[0];
    __syncthreads();
    float sum = 0.f;
    for (int i = t; i < NSTK + 1; i += 1024) {
        float v = (i == 0) ? cash[0] : scores[sidx[i - 1]];
        sum += expf(v - m);
    }
    red[t] = sum;
    __syncthreads();
    for (int s = 512; s > 0; s >>= 1) { if (t < s) red[t] += red[t + s]; __syncthreads(); }
    float inv = 1.f / red[0];
    for (int i = t; i < NSTK + 1; i += 1024) {
        float v = (i == 0) ? cash[0] : scores[sidx[i - 1]];
        out[OUT_W + i] = expf(v - m) * inv;
    }
    if (t == 0) out[OUT_V] = hdr[6] / (float)N_NODES + bc[0];
}

extern "C" void kernel_launch(void* const* d_in, const int* in_sizes, int n_in,
                              void* d_out, int out_size, void* d_ws, size_t ws_size,
                              hipStream_t stream) {
    const float* x    = (const float*)d_in[0];
    const float* ea   = (const float*)d_in[1];
    const float* W1   = (const float*)d_in[2];
    const float* as1  = (const float*)d_in[3];
    const float* ad1  = (const float*)d_in[4];
    const float* We1  = (const float*)d_in[5];
    const float* ae1  = (const float*)d_in[6];
    const float* b1   = (const float*)d_in[7];
    const float* W2   = (const float*)d_in[8];
    const float* as2  = (const float*)d_in[9];
    const float* ad2  = (const float*)d_in[10];
    const float* We2  = (const float*)d_in[11];
    const float* ae2  = (const float*)d_in[12];
    const float* b2   = (const float*)d_in[13];
    const float* Wa   = (const float*)d_in[14];
    const float* ba   = (const float*)d_in[15];
    const float* cash = (const float*)d_in[16];
    const float* Wc   = (const float*)d_in[17];
    const float* bc   = (const float*)d_in[18];
    const int*   ei   = (const int*)d_in[19];
    const int*   sidx = (const int*)d_in[20];

    // workspace layout — all bases 16B-aligned
    char* w = (char*)d_ws;
    float* hdr    = (float*)w;                    // 64 floats
    int*   deg    = (int*)(w + 256);              // N
    int*   cursor = deg + N_NODES;                // N (contiguous with deg -> one memset)
    int*   rowoff = cursor + N_NODES;             // N+4 (padded)
    EPack* epack  = (EPack*)(rowoff + N_NODES + 4);        // EF * 8B
    __half* h1pre = (__half*)(epack + EF);        // N*128 halfs
    float* ssrc1  = (float*)(h1pre + N_NODES * 128);       // N*4
    float* sdst1  = ssrc1 + N_NODES * 4;          // N*4
    float* minv   = sdst1 + N_NODES * 4;          // N*8 (m[4], inv[4] per node)
    float* h1     = minv + N_NODES * 8;           // N*128
    float* h2pre  = h1 + N_NODES * 128;           // N*32
    float* ssrc2  = h2pre + N_NODES * 32;         // N
    float* sdst2  = ssrc2 + N_NODES;              // N
    float* h2     = sdst2 + N_NODES;              // N*32
    float* scores = h2 + N_NODES * 32;            // N

    float* out = (float*)d_out;

    hipMemsetAsync(hdr, 0, 256, stream);
    hipMemsetAsync(deg, 0, 2 * N_NODES * sizeof(int), stream);

    int egrid = (EF + 255) / 256;
    edge_prep<<<2048, 256, 0, stream>>>(ei, ea, deg, out + OUT_EIF, hdr);
    scan_scalar<<<1, SCAN_T, 0, stream>>>(deg, rowoff, We1, ae1, We2, ae2, hdr);
    fill_csr<<<egrid, 256, 0, stream>>>(ei, ea, rowoff, hdr, cursor, epack);

    node_lin1<<<N_NODES, 128, 0, stream>>>(x, W1, as1, ad1, h1pre, ssrc1, sdst1);
    l1_agg<<<(N_NODES + 3) / 4, 256, 0, stream>>>(epack, rowoff, ssrc1, sdst1, h1pre,
                                                  b1, hdr, minv, h1);
    alpha_write<<<2048, 256, 0, stream>>>(ei, ea, ssrc1, sdst1, minv, hdr, out + OUT_A1);
    node_lin2<<<N_NODES, 128, 0, stream>>>(h1, W2, as2, ad2, h2pre, ssrc2, sdst2);
    l2_agg<<<(N_NODES + 3) / 4, 256, 0, stream>>>(epack, rowoff, ssrc2, sdst2, h2pre,
                                                  b2, hdr, h2);
    scores_value<<<(N_NODES + 255) / 256, 256, 0, stream>>>(h2, Wa, ba, Wc, scores, hdr);
    softmax_w<<<1, 1024, 0, stream>>>(scores, sidx, cash, hdr, bc, out);
}

// Round 9
// 588.425 us; speedup vs baseline: 1.8925x; 1.2169x over previous
//
#include <hip/hip_runtime.h>
#include <hip/hip_fp16.h>
#include <math.h>

#define N_NODES 50000
#define N_EDGES 1600000
#define EF      (N_EDGES + N_NODES)
#define NSTK    25000
#define IN_DIM  5
#define HID     32
#define HEADS   4
#define NEG_SLOPE 0.2f

#define SCAN_T  1024
#define CHUNK   ((N_NODES + SCAN_T - 1) / SCAN_T)   // 49
#define JMAX    128                                  // LDS p-cache slots per node

#define NB      256                                  // histogram blocks (1 per CU)
#define NBIN32  (N_NODES / 2)                        // 25000 packed u32 bins (2 u16 each)
#define CHUNK_E ((EF + NB - 1) / NB)                 // 6446 edges per block

// d_out layout (floats): weights[25001] | value[1] | edge_index_full[2*EF] | alpha1[EF*4]
#define OUT_W   0
#define OUT_V   (NSTK + 1)
#define OUT_EIF (NSTK + 2)
#define OUT_A1  (OUT_EIF + 2 * EF)

struct alignas(8) EPack { int s; float av; };        // CSR payload: src node + edge attr

__device__ __forceinline__ float lrelu(float x) { return x > 0.f ? x : NEG_SLOPE * x; }
__device__ __forceinline__ float elu1(float x)  { return x > 0.f ? x : expf(x) - 1.f; }

// ---------------- pass A: per-block LDS histogram (no device atomics) ----------------
// part[b][i] = packed u16 counts {d=2i, d=2i+1} for block b's edge chunk.
// Also accumulates the ea sum into hdr[0].
__global__ __launch_bounds__(256) void hist_pass(const int* __restrict__ ei,
                                                 const float* __restrict__ ea,
                                                 unsigned int* __restrict__ part,
                                                 float* hdr) {
    __shared__ unsigned int cnt[NBIN32];             // 100 KB
    int b = blockIdx.x, t = threadIdx.x;
    for (int i = t; i < NBIN32; i += 256) cnt[i] = 0;
    __syncthreads();
    int e0 = b * CHUNK_E, e1 = min(e0 + CHUNK_E, EF);
    float s = 0.f;
    for (int e = e0 + t; e < e1; e += 256) {
        int d;
        if (e < N_EDGES) { d = ei[N_EDGES + e]; s += ea[e]; }
        else d = e - N_EDGES;
        atomicAdd(&cnt[d >> 1], (d & 1) ? 0x10000u : 1u);   // LDS atomic
    }
    __syncthreads();
    for (int i = t; i < NBIN32; i += 256) part[(size_t)b * NBIN32 + i] = cnt[i];
    #pragma unroll
    for (int off = 1; off < 64; off <<= 1) s += __shfl_xor(s, off);
    if ((t & 63) == 0) atomicAdd(&hdr[0], s);
}

// ---------------- pass B: cross-block prefix (in place) + total degree ----------------
// part[b][d] (u16 halves) becomes the RELATIVE base of block b within bucket d;
// cumulative offsets are bounded by node degree (~150) so u16 is safe.
__global__ void rebase(unsigned int* __restrict__ part, int* __restrict__ deg) {
    int i = blockIdx.x * blockDim.x + threadIdx.x;   // packed bin-pair index
    if (i >= NBIN32) return;
    unsigned int run0 = 0, run1 = 0;
    for (int b = 0; b < NB; b++) {
        size_t idx = (size_t)b * NBIN32 + i;
        unsigned int v = part[idx];
        part[idx] = (run1 << 16) | run0;
        run0 += v & 0xffffu;
        run1 += v >> 16;
    }
    deg[2 * i]     = (int)run0;
    deg[2 * i + 1] = (int)run1;
}

// ---------------- scan (serial-chunk) + scalar prep ----------------
__global__ void scan_scalar(const int* __restrict__ deg, int* __restrict__ rowoff,
                            const float* __restrict__ We1, const float* __restrict__ ae1,
                            const float* __restrict__ We2, const float* __restrict__ ae2,
                            float* hdr) {
    __shared__ int sums[SCAN_T];
    int t = threadIdx.x;

    if (t < 128) {
        float p = We1[t] * ae1[t];
        #pragma unroll
        for (int off = 1; off < 32; off <<= 1) p += __shfl_xor(p, off);
        if ((t & 31) == 0) hdr[1 + (t >> 5)] = p;
        if (t < 32) {
            float q = We2[t] * ae2[t];
            #pragma unroll
            for (int off = 1; off < 32; off <<= 1) q += __shfl_xor(q, off);
            if (t == 0) { hdr[5] = q; hdr[0] = hdr[0] / (float)N_EDGES; }
        }
    }

    int base = t * CHUNK;
    int local = 0;
    for (int i = 0; i < CHUNK; i++) {
        int idx = base + i;
        if (idx < N_NODES) local += deg[idx];
    }
    sums[t] = local;
    __syncthreads();
    #pragma unroll
    for (int off = 1; off < SCAN_T; off <<= 1) {
        int v = (t >= off) ? sums[t - off] : 0;
        __syncthreads();
        sums[t] += v;
        __syncthreads();
    }
    int run = sums[t] - local;          // exclusive prefix of this chunk
    if (t == 0) rowoff[0] = 0;
    for (int i = 0; i < CHUNK; i++) {
        int idx = base + i;
        if (idx < N_NODES) { run += deg[idx]; rowoff[idx + 1] = run; }
    }
}

// ---------------- pass C: scatter edges to CSR slots (LDS counters only) ----------------
__global__ __launch_bounds__(256) void fill_pack(const int* __restrict__ ei,
                                                 const float* __restrict__ ea,
                                                 const int* __restrict__ rowoff,
                                                 const unsigned int* __restrict__ part,
                                                 const float* __restrict__ hdr,
                                                 EPack* __restrict__ epack,
                                                 float* __restrict__ out_eif) {
    __shared__ unsigned int cnt[NBIN32];             // 100 KB
    int b = blockIdx.x, t = threadIdx.x;
    for (int i = t; i < NBIN32; i += 256) cnt[i] = 0;
    __syncthreads();
    float ea_mean = hdr[0];
    const unsigned short* rel = (const unsigned short*)(part + (size_t)b * NBIN32);
    int e0 = b * CHUNK_E, e1 = min(e0 + CHUNK_E, EF);
    for (int e = e0 + t; e < e1; e += 256) {
        int s, d; float av;
        if (e < N_EDGES) { s = ei[e]; d = ei[N_EDGES + e]; av = ea[e]; }
        else             { s = d = e - N_EDGES;            av = ea_mean; }
        unsigned int old = atomicAdd(&cnt[d >> 1], (d & 1) ? 0x10000u : 1u);
        unsigned int local = (d & 1) ? (old >> 16) : (old & 0xffffu);
        int pos = rowoff[d] + (int)rel[d] + (int)local;
        EPack ep; ep.s = s; ep.av = av;
        epack[pos] = ep;
        out_eif[e]      = (float)s;
        out_eif[EF + e] = (float)d;
    }
}

// ---------------- layer 1 linear + attention scalars ----------------
__global__ void node_lin1(const float* __restrict__ x, const float* __restrict__ W1,
                          const float* __restrict__ as1, const float* __restrict__ ad1,
                          __half* __restrict__ h1pre, float* __restrict__ ssrc1,
                          float* __restrict__ sdst1) {
    int n = blockIdx.x, t = threadIdx.x;
    float hv = 0.f;
    #pragma unroll
    for (int k = 0; k < IN_DIM; k++) hv += x[n * IN_DIM + k] * W1[k * 128 + t];
    h1pre[n * 128 + t] = __float2half(hv);
    float a = hv * as1[t];
    float b = hv * ad1[t];
    #pragma unroll
    for (int off = 1; off < 32; off <<= 1) { a += __shfl_xor(a, off); b += __shfl_xor(b, off); }
    if ((t & 31) == 0) { ssrc1[n * 4 + (t >> 5)] = a; sdst1[n * 4 + (t >> 5)] = b; }
}

// ---------------- layer 1 aggregation: one wave per dst node ----------------
__global__ void l1_agg(const EPack* __restrict__ epack, const int* __restrict__ rowoff,
                       const float* __restrict__ ssrc1, const float* __restrict__ sdst1,
                       const __half* __restrict__ h1pre, const float* __restrict__ b1,
                       const float* __restrict__ hdr, float* __restrict__ minv,
                       float* __restrict__ h1) {
    __shared__ float lds_p[4][HEADS][JMAX + 4];
    int wid = threadIdx.x >> 6;
    int n = blockIdx.x * 4 + wid;
    if (n >= N_NODES) return;
    int lane = threadIdx.x & 63;
    int start = rowoff[n], deg = rowoff[n + 1] - start;
    int hl = lane & 3;
    float ce = hdr[1 + hl];
    float sd = sdst1[n * 4 + hl];

    float m = -1e30f;
    for (int k = lane; k < deg * 4; k += 64) {
        EPack ep = epack[start + (k >> 2)];
        m = fmaxf(m, lrelu(ssrc1[ep.s * 4 + hl] + sd + ep.av * ce));
    }
    #pragma unroll
    for (int off = 4; off < 64; off <<= 1) m = fmaxf(m, __shfl_xor(m, off));

    float den = 0.f;
    for (int k = lane; k < deg * 4; k += 64) {
        int j = k >> 2;
        EPack ep = epack[start + j];
        float pv = expf(lrelu(ssrc1[ep.s * 4 + hl] + sd + ep.av * ce) - m);
        den += pv;
        if (j < JMAX) lds_p[wid][hl][j] = pv;
    }
    #pragma unroll
    for (int off = 4; off < 64; off <<= 1) den += __shfl_xor(den, off);
    float inv = 1.f / (den + 1e-16f);

    // publish m/inv per head for the alpha_write kernel
    {
        float mh = __shfl(m,  lane & 3);
        float ih = __shfl(inv, lane & 3);
        if (lane < 8) minv[n * 8 + lane] = (lane < 4) ? mh : ih;
    }

    __builtin_amdgcn_wave_barrier();   // order LDS p writes before acc reads (no cross-wave dep)

    int sub = lane & 15, el = lane >> 4;
    int h = sub >> 2;                  // this lane's head (channels sub*8..sub*8+7)
    float invh = __shfl(inv, h);
    int jcap = deg < JMAX ? deg : JMAX;
    float acc[8];
    #pragma unroll
    for (int i = 0; i < 8; i++) acc[i] = 0.f;

    for (int j0 = 0; j0 < jcap; j0 += 4) {
        int j = j0 + el;
        float a = 0.f; int s = 0;
        if (j < jcap) { a = lds_p[wid][h][j] * invh; s = epack[start + j].s; }
        const uint4 rv = *(const uint4*)(h1pre + (size_t)s * 128 + sub * 8);
        const __half2* hp = (const __half2*)&rv;
        #pragma unroll
        for (int i = 0; i < 4; i++) {
            float2 f = __half22float2(hp[i]);
            acc[2 * i]     += a * f.x;
            acc[2 * i + 1] += a * f.y;
        }
    }
    if (deg > JMAX) {                  // rare fallback: recompute alpha
        float mh = __shfl(m, h), sdh = __shfl(sd, h), ceh = __shfl(ce, h);
        for (int j0 = JMAX; j0 < deg; j0 += 4) {
            int j = j0 + el;
            float a = 0.f; int s = 0;
            if (j < deg) {
                EPack ep = epack[start + j];
                s = ep.s;
                a = expf(lrelu(ssrc1[s * 4 + h] + sdh + ep.av * ceh) - mh) * invh;
            }
            const uint4 rv = *(const uint4*)(h1pre + (size_t)s * 128 + sub * 8);
            const __half2* hp = (const __half2*)&rv;
            #pragma unroll
            for (int i = 0; i < 4; i++) {
                float2 f = __half22float2(hp[i]);
                acc[2 * i]     += a * f.x;
                acc[2 * i + 1] += a * f.y;
            }
        }
    }

    #pragma unroll
    for (int i = 0; i < 8; i++) {
        acc[i] += __shfl_xor(acc[i], 16);
        acc[i] += __shfl_xor(acc[i], 32);
    }
    if (lane < 16) {
        int c0 = lane * 8;
        float4 bb0 = *(const float4*)(b1 + c0);
        float4 bb1 = *(const float4*)(b1 + c0 + 4);
        float4 r0 = make_float4(elu1(acc[0] + bb0.x), elu1(acc[1] + bb0.y),
                                elu1(acc[2] + bb0.z), elu1(acc[3] + bb0.w));
        float4 r1 = make_float4(elu1(acc[4] + bb1.x), elu1(acc[5] + bb1.y),
                                elu1(acc[6] + bb1.z), elu1(acc[7] + bb1.w));
        *(float4*)(h1 + n * 128 + c0)     = r0;
        *(float4*)(h1 + n * 128 + c0 + 4) = r1;
    }
}

// ---------------- alpha1 output: edge-parallel, original order -> sequential writes ----------------
__global__ void alpha_write(const int* __restrict__ ei, const float* __restrict__ ea,
                            const float* __restrict__ ssrc1, const float* __restrict__ sdst1,
                            const float* __restrict__ minv, const float* __restrict__ hdr,
                            float* __restrict__ alpha_out) {
    float ea_mean = hdr[0];
    float ce0 = hdr[1], ce1 = hdr[2], ce2 = hdr[3], ce3 = hdr[4];
    for (int e = blockIdx.x * blockDim.x + threadIdx.x; e < EF; e += gridDim.x * blockDim.x) {
        int s, d; float av;
        if (e < N_EDGES) { s = ei[e]; d = ei[N_EDGES + e]; av = ea[e]; }
        else             { s = d = e - N_EDGES;            av = ea_mean; }
        float4 ss = *(const float4*)(ssrc1 + (size_t)s * 4);
        float4 dd = *(const float4*)(sdst1 + (size_t)d * 4);
        float4 mm = *(const float4*)(minv + (size_t)d * 8);
        float4 iv = *(const float4*)(minv + (size_t)d * 8 + 4);
        float a0 = expf(lrelu(ss.x + dd.x + av * ce0) - mm.x) * iv.x;
        float a1 = expf(lrelu(ss.y + dd.y + av * ce1) - mm.y) * iv.y;
        float a2 = expf(lrelu(ss.z + dd.z + av * ce2) - mm.z) * iv.z;
        float a3 = expf(lrelu(ss.w + dd.w + av * ce3) - mm.w) * iv.w;
        float2* ap = (float2*)(alpha_out + (size_t)e * 4);
        ap[0] = make_float2(a0, a1);
        ap[1] = make_float2(a2, a3);
    }
}

// ---------------- layer 2 linear + attention scalars ----------------
__global__ void node_lin2(const float* __restrict__ h1, const float* __restrict__ W2,
                          const float* __restrict__ as2, const float* __restrict__ ad2,
                          float* __restrict__ h2pre, float* __restrict__ ssrc2,
                          float* __restrict__ sdst2) {
    __shared__ float sh[128];
    __shared__ float red[128];
    int n = blockIdx.x, t = threadIdx.x;
    sh[t] = h1[n * 128 + t];
    __syncthreads();
    int c = t & 31, q = t >> 5;
    float p = 0.f;
    #pragma unroll
    for (int k = 0; k < 32; k++) p += sh[q * 32 + k] * W2[(q * 32 + k) * 32 + c];
    red[t] = p;
    __syncthreads();
    if (t < 32) {
        float hv = red[t] + red[t + 32] + red[t + 64] + red[t + 96];
        h2pre[n * 32 + t] = hv;
        float a = hv * as2[t], b = hv * ad2[t];
        #pragma unroll
        for (int off = 1; off < 32; off <<= 1) { a += __shfl_xor(a, off); b += __shfl_xor(b, off); }
        if (t == 0) { ssrc2[n] = a; sdst2[n] = b; }
    }
}

// ---------------- layer 2 aggregation: same LDS-p + 4-edge-ILP structure ----------------
__global__ void l2_agg(const EPack* __restrict__ epack, const int* __restrict__ rowoff,
                       const float* __restrict__ ssrc2, const float* __restrict__ sdst2,
                       const float* __restrict__ h2pre, const float* __restrict__ b2,
                       const float* __restrict__ hdr, float* __restrict__ h2) {
    __shared__ float lds_q[4][JMAX + 4];
    int wid = threadIdx.x >> 6;
    int n = blockIdx.x * 4 + wid;
    if (n >= N_NODES) return;
    int lane = threadIdx.x & 63;
    int start = rowoff[n], deg = rowoff[n + 1] - start;
    float ce = hdr[5];
    float sd = sdst2[n];

    float m = -1e30f;
    for (int k = lane; k < deg; k += 64) {
        EPack ep = epack[start + k];
        m = fmaxf(m, lrelu(ssrc2[ep.s] + sd + ep.av * ce));
    }
    #pragma unroll
    for (int off = 1; off < 64; off <<= 1) m = fmaxf(m, __shfl_xor(m, off));

    float den = 0.f;
    for (int k = lane; k < deg; k += 64) {
        EPack ep = epack[start + k];
        float pv = expf(lrelu(ssrc2[ep.s] + sd + ep.av * ce) - m);
        den += pv;
        if (k < JMAX) lds_q[wid][k] = pv;
    }
    #pragma unroll
    for (int off = 1; off < 64; off <<= 1) den += __shfl_xor(den, off);
    float inv = 1.f / (den + 1e-16f);

    __builtin_amdgcn_wave_barrier();

    int sub = lane & 15, el = lane >> 4;   // edge slot el, channel pair sub*2
    int jcap = deg < JMAX ? deg : JMAX;
    float acc0 = 0.f, acc1 = 0.f;
    for (int j0 = 0; j0 < jcap; j0 += 4) {
        int j = j0 + el;
        float a = 0.f; int s = 0;
        if (j < jcap) { a = lds_q[wid][j] * inv; s = epack[start + j].s; }
        float2 f = *(const float2*)(h2pre + (size_t)s * 32 + sub * 2);
        acc0 += a * f.x;
        acc1 += a * f.y;
    }
    if (deg > JMAX) {
        for (int j0 = JMAX; j0 < deg; j0 += 4) {
            int j = j0 + el;
            float a = 0.f; int s = 0;
            if (j < deg) {
                EPack ep = epack[start + j];
                s = ep.s;
                a = expf(lrelu(ssrc2[s] + sd + ep.av * ce) - m) * inv;
            }
            float2 f = *(const float2*)(h2pre + (size_t)s * 32 + sub * 2);
            acc0 += a * f.x;
            acc1 += a * f.y;
        }
    }
    acc0 += __shfl_xor(acc0, 16); acc0 += __shfl_xor(acc0, 32);
    acc1 += __shfl_xor(acc1, 16); acc1 += __shfl_xor(acc1, 32);
    if (lane < 16) {
        float2 bb = *(const float2*)(b2 + lane * 2);
        *(float2*)(h2 + n * 32 + lane * 2) =
            make_float2(elu1(acc0 + bb.x), elu1(acc1 + bb.y));
    }
}

// ---------------- heads: scores (actor) + value accumulation (critic) ----------------
__global__ void scores_value(const float* __restrict__ h2, const float* __restrict__ Wa,
                             const float* __restrict__ ba, const float* __restrict__ Wc,
                             float* __restrict__ scores, float* hdr) {
    int n = blockIdx.x * blockDim.x + threadIdx.x;
    float vc = 0.f;
    if (n < N_NODES) {
        float va = 0.f;
        #pragma unroll
        for (int cidx = 0; cidx < 32; cidx++) {
            float hv = h2[n * 32 + cidx];
            va += hv * Wa[cidx];
            vc += hv * Wc[cidx];
        }
        scores[n] = va + ba[0];
    }
    #pragma unroll
    for (int off = 1; off < 64; off <<= 1) vc += __shfl_xor(vc, off);
    if ((threadIdx.x & 63) == 0) atomicAdd(&hdr[6], vc);
}

// ---------------- portfolio softmax + value write ----------------
__global__ void softmax_w(const float* __restrict__ scores, const int* __restrict__ sidx,
                          const float* __restrict__ cash, const float* __restrict__ hdr,
                          const float* __restrict__ bc, float* __restrict__ out) {
    __shared__ float red[1024];
    int t = threadIdx.x;
    float m = -1e30f;
    for (int i = t; i < NSTK + 1; i += 1024) {
        float v = (i == 0) ? cash[0] : scores[sidx[i - 1]];
        m = fmaxf(m, v);
    }
    red[t] = m;
    __syncthreads();
    for (int s = 512; s > 0; s >>= 1) { if (t < s) red[t] = fmaxf(red[t], red[t + s]); __syncthreads(); }
    m = red[0];
    __syncthreads();
    float sum = 0.f;
    for (int i = t; i < NSTK + 1; i += 1024) {
        float v = (i == 0) ? cash[0] : scores[sidx[i - 1]];
        sum += expf(v - m);
    }
    red[t] = sum;
    __syncthreads();
    for (int s = 512; s > 0; s >>= 1) { if (t < s) red[t] += red[t + s]; __syncthreads(); }
    float inv = 1.f / red[0];
    for (int i = t; i < NSTK + 1; i += 1024) {
        float v = (i == 0) ? cash[0] : scores[sidx[i - 1]];
        out[OUT_W + i] = expf(v - m) * inv;
    }
    if (t == 0) out[OUT_V] = hdr[6] / (float)N_NODES + bc[0];
}

extern "C" void kernel_launch(void* const* d_in, const int* in_sizes, int n_in,
                              void* d_out, int out_size, void* d_ws, size_t ws_size,
                              hipStream_t stream) {
    const float* x    = (const float*)d_in[0];
    const float* ea   = (const float*)d_in[1];
    const float* W1   = (const float*)d_in[2];
    const float* as1  = (const float*)d_in[3];
    const float* ad1  = (const float*)d_in[4];
    const float* We1  = (const float*)d_in[5];
    const float* ae1  = (const float*)d_in[6];
    const float* b1   = (const float*)d_in[7];
    const float* W2   = (const float*)d_in[8];
    const float* as2  = (const float*)d_in[9];
    const float* ad2  = (const float*)d_in[10];
    const float* We2  = (const float*)d_in[11];
    const float* ae2  = (const float*)d_in[12];
    const float* b2   = (const float*)d_in[13];
    const float* Wa   = (const float*)d_in[14];
    const float* ba   = (const float*)d_in[15];
    const float* cash = (const float*)d_in[16];
    const float* Wc   = (const float*)d_in[17];
    const float* bc   = (const float*)d_in[18];
    const int*   ei   = (const int*)d_in[19];
    const int*   sidx = (const int*)d_in[20];

    // workspace layout — all bases 16B-aligned, total ~68.5 MB (proven envelope).
    // NOTE: `part` (25.6 MB, used only by hist/rebase/fill_pack) ALIASES `h1`
    // (25.6 MB, first written later by l1_agg) — lifetimes are stream-disjoint.
    char* w = (char*)d_ws;
    float* hdr    = (float*)w;                    // 64 floats
    int*   deg    = (int*)(w + 256);              // N
    int*   rowoff = deg + N_NODES;                // N+4 (padded)
    EPack* epack  = (EPack*)(rowoff + N_NODES + 4);        // EF * 8B
    __half* h1pre = (__half*)(epack + EF);        // N*128 halfs
    float* ssrc1  = (float*)(h1pre + N_NODES * 128);       // N*4
    float* sdst1  = ssrc1 + N_NODES * 4;          // N*4
    float* minv   = sdst1 + N_NODES * 4;          // N*8 (m[4], inv[4] per node)
    float* h1     = minv + N_NODES * 8;           // N*128 floats
    unsigned int* part = (unsigned int*)h1;       // NB*NBIN32 u32 = 25.6MB (alias, early phase)
    float* h2pre  = h1 + N_NODES * 128;           // N*32
    float* ssrc2  = h2pre + N_NODES * 32;         // N
    float* sdst2  = ssrc2 + N_NODES;              // N
    float* h2     = sdst2 + N_NODES;              // N*32
    float* scores = h2 + N_NODES * 32;            // N

    float* out = (float*)d_out;

    hipMemsetAsync(hdr, 0, 256, stream);

    hist_pass<<<NB, 256, 0, stream>>>(ei, ea, part, hdr);
    rebase<<<(NBIN32 + 255) / 256, 256, 0, stream>>>(part, deg);
    scan_scalar<<<1, SCAN_T, 0, stream>>>(deg, rowoff, We1, ae1, We2, ae2, hdr);
    fill_pack<<<NB, 256, 0, stream>>>(ei, ea, rowoff, part, hdr, epack, out + OUT_EIF);

    node_lin1<<<N_NODES, 128, 0, stream>>>(x, W1, as1, ad1, h1pre, ssrc1, sdst1);
    l1_agg<<<(N_NODES + 3) / 4, 256, 0, stream>>>(epack, rowoff, ssrc1, sdst1, h1pre,
                                                  b1, hdr, minv, h1);
    alpha_write<<<2048, 256, 0, stream>>>(ei, ea, ssrc1, sdst1, minv, hdr, out + OUT_A1);
    node_lin2<<<N_NODES, 128, 0, stream>>>(h1, W2, as2, ad2, h2pre, ssrc2, sdst2);
    l2_agg<<<(N_NODES + 3) / 4, 256, 0, stream>>>(epack, rowoff, ssrc2, sdst2, h2pre,
                                                  b2, hdr, h2);
    scores_value<<<(N_NODES + 255) / 256, 256, 0, stream>>>(h2, Wa, ba, Wc, scores, hdr);
    softmax_w<<<1, 1024, 0, stream>>>(scores, sidx, cash, hdr, bc, out);
}

// Round 14
// 547.554 us; speedup vs baseline: 2.0337x; 1.0746x over previous
//
#include <hip/hip_runtime.h>
#include <hip/hip_fp16.h>
#include <math.h>

#define N_NODES 50000
#define N_EDGES 1600000
#define EF      (N_EDGES + N_NODES)
#define NSTK    25000
#define IN_DIM  5
#define HID     32
#define HEADS   4
#define NEG_SLOPE 0.2f

#define SCAN_T  1024
#define CHUNK   ((N_NODES + SCAN_T - 1) / SCAN_T)   // 49
#define JMAX    128                                  // LDS p-cache slots per node

#define NB      256                                  // histogram blocks (1 per CU)
#define NBIN32  (N_NODES / 2)                        // 25000 packed u32 bins (2 u16 each)
#define CHUNK_E ((EF + NB - 1) / NB)                 // 6446 edges per block

// d_out layout (floats): weights[25001] | value[1] | edge_index_full[2*EF] | alpha1[EF*4]
#define OUT_W   0
#define OUT_V   (NSTK + 1)
#define OUT_EIF (NSTK + 2)
#define OUT_A1  (OUT_EIF + 2 * EF)

struct alignas(8) EPack { int s; float av; };        // CSR payload: src node + edge attr

__device__ __forceinline__ float lrelu(float x) { return x > 0.f ? x : NEG_SLOPE * x; }
__device__ __forceinline__ float elu1(float x)  { return x > 0.f ? x : expf(x) - 1.f; }

// ---------------- pass A: per-block LDS histogram (no device atomics) ----------------
__global__ __launch_bounds__(256) void hist_pass(const int* __restrict__ ei,
                                                 const float* __restrict__ ea,
                                                 unsigned int* __restrict__ part,
                                                 float* hdr) {
    __shared__ unsigned int cnt[NBIN32];             // 100 KB
    int b = blockIdx.x, t = threadIdx.x;
    for (int i = t; i < NBIN32; i += 256) cnt[i] = 0;
    __syncthreads();
    int e0 = b * CHUNK_E, e1 = min(e0 + CHUNK_E, EF);
    float s = 0.f;
    for (int e = e0 + t; e < e1; e += 256) {
        int d;
        if (e < N_EDGES) { d = ei[N_EDGES + e]; s += ea[e]; }
        else d = e - N_EDGES;
        atomicAdd(&cnt[d >> 1], (d & 1) ? 0x10000u : 1u);   // LDS atomic
    }
    __syncthreads();
    for (int i = t; i < NBIN32; i += 256) part[(size_t)b * NBIN32 + i] = cnt[i];
    #pragma unroll
    for (int off = 1; off < 64; off <<= 1) s += __shfl_xor(s, off);
    if ((t & 63) == 0) atomicAdd(&hdr[0], s);
}

// ---------------- pass B: cross-block prefix (in place) + total degree ----------------
__global__ void rebase(unsigned int* __restrict__ part, int* __restrict__ deg) {
    int i = blockIdx.x * blockDim.x + threadIdx.x;   // packed bin-pair index
    if (i >= NBIN32) return;
    unsigned int run0 = 0, run1 = 0;
    for (int b = 0; b < NB; b++) {
        size_t idx = (size_t)b * NBIN32 + i;
        unsigned int v = part[idx];
        part[idx] = (run1 << 16) | run0;
        run0 += v & 0xffffu;
        run1 += v >> 16;
    }
    deg[2 * i]     = (int)run0;
    deg[2 * i + 1] = (int)run1;
}

// ---------------- scan (serial-chunk) + scalar prep ----------------
__global__ void scan_scalar(const int* __restrict__ deg, int* __restrict__ rowoff,
                            const float* __restrict__ We1, const float* __restrict__ ae1,
                            const float* __restrict__ We2, const float* __restrict__ ae2,
                            float* hdr) {
    __shared__ int sums[SCAN_T];
    int t = threadIdx.x;

    if (t < 128) {
        float p = We1[t] * ae1[t];
        #pragma unroll
        for (int off = 1; off < 32; off <<= 1) p += __shfl_xor(p, off);
        if ((t & 31) == 0) hdr[1 + (t >> 5)] = p;
        if (t < 32) {
            float q = We2[t] * ae2[t];
            #pragma unroll
            for (int off = 1; off < 32; off <<= 1) q += __shfl_xor(q, off);
            if (t == 0) { hdr[5] = q; hdr[0] = hdr[0] / (float)N_EDGES; }
        }
    }

    int base = t * CHUNK;
    int local = 0;
    for (int i = 0; i < CHUNK; i++) {
        int idx = base + i;
        if (idx < N_NODES) local += deg[idx];
    }
    sums[t] = local;
    __syncthreads();
    #pragma unroll
    for (int off = 1; off < SCAN_T; off <<= 1) {
        int v = (t >= off) ? sums[t - off] : 0;
        __syncthreads();
        sums[t] += v;
        __syncthreads();
    }
    int run = sums[t] - local;          // exclusive prefix of this chunk
    if (t == 0) rowoff[0] = 0;
    for (int i = 0; i < CHUNK; i++) {
        int idx = base + i;
        if (idx < N_NODES) { run += deg[idx]; rowoff[idx + 1] = run; }
    }
}

// ---------------- pass C: scatter edges to CSR slots (LDS counters only) ----------------
__global__ __launch_bounds__(256) void fill_pack(const int* __restrict__ ei,
                                                 const float* __restrict__ ea,
                                                 const int* __restrict__ rowoff,
                                                 const unsigned int* __restrict__ part,
                                                 const float* __restrict__ hdr,
                                                 EPack* __restrict__ epack,
                                                 float* __restrict__ out_eif) {
    __shared__ unsigned int cnt[NBIN32];             // 100 KB
    int b = blockIdx.x, t = threadIdx.x;
    for (int i = t; i < NBIN32; i += 256) cnt[i] = 0;
    __syncthreads();
    float ea_mean = hdr[0];
    const unsigned short* rel = (const unsigned short*)(part + (size_t)b * NBIN32);
    int e0 = b * CHUNK_E, e1 = min(e0 + CHUNK_E, EF);
    for (int e = e0 + t; e < e1; e += 256) {
        int s, d; float av;
        if (e < N_EDGES) { s = ei[e]; d = ei[N_EDGES + e]; av = ea[e]; }
        else             { s = d = e - N_EDGES;            av = ea_mean; }
        unsigned int old = atomicAdd(&cnt[d >> 1], (d & 1) ? 0x10000u : 1u);
        unsigned int local = (d & 1) ? (old >> 16) : (old & 0xffffu);
        int pos = rowoff[d] + (int)rel[d] + (int)local;
        EPack ep; ep.s = s; ep.av = av;
        epack[pos] = ep;
        out_eif[e]      = (float)s;
        out_eif[EF + e] = (float)d;
    }
}

// ---------------- layer 1 linear + attention scalars ----------------
__global__ void node_lin1(const float* __restrict__ x, const float* __restrict__ W1,
                          const float* __restrict__ as1, const float* __restrict__ ad1,
                          __half* __restrict__ h1pre, float* __restrict__ ssrc1,
                          float* __restrict__ sdst1) {
    int n = blockIdx.x, t = threadIdx.x;
    float hv = 0.f;
    #pragma unroll
    for (int k = 0; k < IN_DIM; k++) hv += x[n * IN_DIM + k] * W1[k * 128 + t];
    h1pre[n * 128 + t] = __float2half(hv);
    float a = hv * as1[t];
    float b = hv * ad1[t];
    #pragma unroll
    for (int off = 1; off < 32; off <<= 1) { a += __shfl_xor(a, off); b += __shfl_xor(b, off); }
    if ((t & 31) == 0) { ssrc1[n * 4 + (t >> 5)] = a; sdst1[n * 4 + (t >> 5)] = b; }
}

// ---------------- layer 1 aggregation + fused layer-2 linear ----------------
// pass1: lg -> LDS + running max (ONE global sweep).  pass2: LDS-only exp/den.
// acc: 4 edges/iter, 16 lanes/edge, 16B fp16 gather.  epilogue: h1 row -> LDS,
// h2pre = h1 @ W2 (+ ssrc2/sdst2) computed in-block -> node_lin2 kernel deleted.
__global__ void l1_agg(const EPack* __restrict__ epack, const int* __restrict__ rowoff,
                       const float* __restrict__ ssrc1, const float* __restrict__ sdst1,
                       const __half* __restrict__ h1pre, const float* __restrict__ b1,
                       const float* __restrict__ W2, const float* __restrict__ as2,
                       const float* __restrict__ ad2, const float* __restrict__ hdr,
                       float* __restrict__ minv, float* __restrict__ h2pre,
                       float* __restrict__ ssrc2, float* __restrict__ sdst2) {
    __shared__ float lds_p[4][HEADS][JMAX + 4];
    __shared__ float lds_h[4][132];
    int wid = threadIdx.x >> 6;
    int n = blockIdx.x * 4 + wid;
    if (n >= N_NODES) return;
    int lane = threadIdx.x & 63;
    int start = rowoff[n], deg = rowoff[n + 1] - start;
    int hl = lane & 3;
    float ce = hdr[1 + hl];
    float sd = sdst1[n * 4 + hl];
    int jcap = deg < JMAX ? deg : JMAX;

    // pass 1: single global sweep — lg to LDS, track max
    float m = -1e30f;
    for (int k = lane; k < deg * 4; k += 64) {
        int j = k >> 2;
        EPack ep = epack[start + j];
        float lg = lrelu(ssrc1[ep.s * 4 + hl] + sd + ep.av * ce);
        m = fmaxf(m, lg);
        if (j < JMAX) lds_p[wid][hl][j] = lg;
    }
    #pragma unroll
    for (int off = 4; off < 64; off <<= 1) m = fmaxf(m, __shfl_xor(m, off));

    // pass 2: LDS-only (each lane re-reads its own slots) — p = exp(lg-m), den
    float den = 0.f;
    for (int k = lane; k < jcap * 4; k += 64) {
        int j = k >> 2;
        float pv = expf(lds_p[wid][hl][j] - m);
        lds_p[wid][hl][j] = pv;
        den += pv;
    }
    if (deg > JMAX) {                  // rare tail: recompute from global
        for (int k = JMAX * 4 + lane; k < deg * 4; k += 64) {
            int j = k >> 2;
            EPack ep = epack[start + j];
            den += expf(lrelu(ssrc1[ep.s * 4 + hl] + sd + ep.av * ce) - m);
        }
    }
    #pragma unroll
    for (int off = 4; off < 64; off <<= 1) den += __shfl_xor(den, off);
    float inv = 1.f / (den + 1e-16f);

    // publish m/inv per head for the alpha_write kernel
    {
        float mh = __shfl(m,  lane & 3);
        float ih = __shfl(inv, lane & 3);
        if (lane < 8) minv[n * 8 + lane] = (lane < 4) ? mh : ih;
    }

    __builtin_amdgcn_wave_barrier();   // order LDS p writes before cross-lane acc reads

    int sub = lane & 15, el = lane >> 4;
    int h = sub >> 2;                  // this lane's head (channels sub*8..sub*8+7)
    float invh = __shfl(inv, h);
    float acc[8];
    #pragma unroll
    for (int i = 0; i < 8; i++) acc[i] = 0.f;

    for (int j0 = 0; j0 < jcap; j0 += 4) {
        int j = j0 + el;
        float a = 0.f; int s = 0;
        if (j < jcap) { a = lds_p[wid][h][j] * invh; s = epack[start + j].s; }
        const uint4 rv = *(const uint4*)(h1pre + (size_t)s * 128 + sub * 8);
        const __half2* hp = (const __half2*)&rv;
        #pragma unroll
        for (int i = 0; i < 4; i++) {
            float2 f = __half22float2(hp[i]);
            acc[2 * i]     += a * f.x;
            acc[2 * i + 1] += a * f.y;
        }
    }
    if (deg > JMAX) {                  // rare fallback: recompute alpha
        float mh = __shfl(m, h), sdh = __shfl(sd, h), ceh = __shfl(ce, h);
        for (int j0 = JMAX; j0 < deg; j0 += 4) {
            int j = j0 + el;
            float a = 0.f; int s = 0;
            if (j < deg) {
                EPack ep = epack[start + j];
                s = ep.s;
                a = expf(lrelu(ssrc1[s * 4 + h] + sdh + ep.av * ceh) - mh) * invh;
            }
            const uint4 rv = *(const uint4*)(h1pre + (size_t)s * 128 + sub * 8);
            const __half2* hp = (const __half2*)&rv;
            #pragma unroll
            for (int i = 0; i < 4; i++) {
                float2 f = __half22float2(hp[i]);
                acc[2 * i]     += a * f.x;
                acc[2 * i + 1] += a * f.y;
            }
        }
    }

    #pragma unroll
    for (int i = 0; i < 8; i++) {
        acc[i] += __shfl_xor(acc[i], 16);
        acc[i] += __shfl_xor(acc[i], 32);
    }
    // h1 row (bias + elu) -> LDS staging for the fused W2 matmul
    if (lane < 16) {
        int c0 = lane * 8;
        float4 bb0 = *(const float4*)(b1 + c0);
        float4 bb1 = *(const float4*)(b1 + c0 + 4);
        float4 r0 = make_float4(elu1(acc[0] + bb0.x), elu1(acc[1] + bb0.y),
                                elu1(acc[2] + bb0.z), elu1(acc[3] + bb0.w));
        float4 r1 = make_float4(elu1(acc[4] + bb1.x), elu1(acc[5] + bb1.y),
                                elu1(acc[6] + bb1.z), elu1(acc[7] + bb1.w));
        *(float4*)(&lds_h[wid][c0])     = r0;
        *(float4*)(&lds_h[wid][c0 + 4]) = r1;
    }
    __builtin_amdgcn_wave_barrier();   // lds_h writes before cross-lane reads

    // fused node_lin2: h2pre[n][c] = sum_k h1[k] * W2[k][c]
    int c = lane & 31, half = lane >> 5;
    float acc2 = 0.f;
    int kbase = half * 64;
    #pragma unroll 8
    for (int k = 0; k < 64; k++)
        acc2 += lds_h[wid][kbase + k] * W2[(kbase + k) * 32 + c];
    acc2 += __shfl_xor(acc2, 32);      // all lanes now hold channel (lane&31)'s value
    float a2 = acc2 * as2[c];
    float d2 = acc2 * ad2[c];
    #pragma unroll
    for (int off = 1; off < 32; off <<= 1) {
        a2 += __shfl_xor(a2, off);
        d2 += __shfl_xor(d2, off);
    }
    if (lane < 32) h2pre[n * 32 + c] = acc2;
    if (lane == 0) { ssrc2[n] = a2; sdst2[n] = d2; }
}

// ---------------- alpha1 output: edge-parallel, original order -> sequential writes ----------------
__global__ void alpha_write(const int* __restrict__ ei, const float* __restrict__ ea,
                            const float* __restrict__ ssrc1, const float* __restrict__ sdst1,
                            const float* __restrict__ minv, const float* __restrict__ hdr,
                            float* __restrict__ alpha_out) {
    float ea_mean = hdr[0];
    float ce0 = hdr[1], ce1 = hdr[2], ce2 = hdr[3], ce3 = hdr[4];
    for (int e = blockIdx.x * blockDim.x + threadIdx.x; e < EF; e += gridDim.x * blockDim.x) {
        int s, d; float av;
        if (e < N_EDGES) { s = ei[e]; d = ei[N_EDGES + e]; av = ea[e]; }
        else             { s = d = e - N_EDGES;            av = ea_mean; }
        float4 ss = *(const float4*)(ssrc1 + (size_t)s * 4);
        float4 dd = *(const float4*)(sdst1 + (size_t)d * 4);
        float4 mm = *(const float4*)(minv + (size_t)d * 8);
        float4 iv = *(const float4*)(minv + (size_t)d * 8 + 4);
        float a0 = expf(lrelu(ss.x + dd.x + av * ce0) - mm.x) * iv.x;
        float a1 = expf(lrelu(ss.y + dd.y + av * ce1) - mm.y) * iv.y;
        float a2 = expf(lrelu(ss.z + dd.z + av * ce2) - mm.z) * iv.z;
        float a3 = expf(lrelu(ss.w + dd.w + av * ce3) - mm.w) * iv.w;
        float2* ap = (float2*)(alpha_out + (size_t)e * 4);
        ap[0] = make_float2(a0, a1);
        ap[1] = make_float2(a2, a3);
    }
}

// ---------------- layer 2 aggregation: lg-in-LDS + 4-edge-ILP ----------------
__global__ void l2_agg(const EPack* __restrict__ epack, const int* __restrict__ rowoff,
                       const float* __restrict__ ssrc2, const float* __restrict__ sdst2,
                       const float* __restrict__ h2pre, const float* __restrict__ b2,
                       const float* __restrict__ hdr, float* __restrict__ h2) {
    __shared__ float lds_q[4][JMAX + 4];
    int wid = threadIdx.x >> 6;
    int n = blockIdx.x * 4 + wid;
    if (n >= N_NODES) return;
    int lane = threadIdx.x & 63;
    int start = rowoff[n], deg = rowoff[n + 1] - start;
    float ce = hdr[5];
    float sd = sdst2[n];
    int jcap = deg < JMAX ? deg : JMAX;

    // pass 1: single global sweep — lg to LDS, track max
    float m = -1e30f;
    for (int k = lane; k < deg; k += 64) {
        EPack ep = epack[start + k];
        float lg = lrelu(ssrc2[ep.s] + sd + ep.av * ce);
        m = fmaxf(m, lg);
        if (k < JMAX) lds_q[wid][k] = lg;
    }
    #pragma unroll
    for (int off = 1; off < 64; off <<= 1) m = fmaxf(m, __shfl_xor(m, off));

    // pass 2: LDS-only exp/den
    float den = 0.f;
    for (int k = lane; k < jcap; k += 64) {
        float pv = expf(lds_q[wid][k] - m);
        lds_q[wid][k] = pv;
        den += pv;
    }
    if (deg > JMAX) {
        for (int k = JMAX + lane; k < deg; k += 64) {
            EPack ep = epack[start + k];
            den += expf(lrelu(ssrc2[ep.s] + sd + ep.av * ce) - m);
        }
    }
    #pragma unroll
    for (int off = 1; off < 64; off <<= 1) den += __shfl_xor(den, off);
    float inv = 1.f / (den + 1e-16f);

    __builtin_amdgcn_wave_barrier();

    int sub = lane & 15, el = lane >> 4;   // edge slot el, channel pair sub*2
    float acc0 = 0.f, acc1 = 0.f;
    for (int j0 = 0; j0 < jcap; j0 += 4) {
        int j = j0 + el;
        float a = 0.f; int s = 0;
        if (j < jcap) { a = lds_q[wid][j] * inv; s = epack[start + j].s; }
        float2 f = *(const float2*)(h2pre + (size_t)s * 32 + sub * 2);
        acc0 += a * f.x;
        acc1 += a * f.y;
    }
    if (deg > JMAX) {
        for (int j0 = JMAX; j0 < deg; j0 += 4) {
            int j = j0 + el;
            float a = 0.f; int s = 0;
            if (j < deg) {
                EPack ep = epack[start + j];
                s = ep.s;
                a = expf(lrelu(ssrc2[s] + sd + ep.av * ce) - m) * inv;
            }
            float2 f = *(const float2*)(h2pre + (size_t)s * 32 + sub * 2);
            acc0 += a * f.x;
            acc1 += a * f.y;
        }
    }
    acc0 += __shfl_xor(acc0, 16); acc0 += __shfl_xor(acc0, 32);
    acc1 += __shfl_xor(acc1, 16); acc1 += __shfl_xor(acc1, 32);
    if (lane < 16) {
        float2 bb = *(const float2*)(b2 + lane * 2);
        *(float2*)(h2 + n * 32 + lane * 2) =
            make_float2(elu1(acc0 + bb.x), elu1(acc1 + bb.y));
    }
}

// ---------------- heads: scores (actor) + value accumulation (critic) ----------------
__global__ void scores_value(const float* __restrict__ h2, const float* __restrict__ Wa,
                             const float* __restrict__ ba, const float* __restrict__ Wc,
                             float* __restrict__ scores, float* hdr) {
    int n = blockIdx.x * blockDim.x + threadIdx.x;
    float vc = 0.f;
    if (n < N_NODES) {
        float va = 0.f;
        #pragma unroll
        for (int cidx = 0; cidx < 32; cidx++) {
            float hv = h2[n * 32 + cidx];
            va += hv * Wa[cidx];
            vc += hv * Wc[cidx];
        }
        scores[n] = va + ba[0];
    }
    #pragma unroll
    for (int off = 1; off < 64; off <<= 1) vc += __shfl_xor(vc, off);
    if ((threadIdx.x & 63) == 0) atomicAdd(&hdr[6], vc);
}

// ---------------- portfolio softmax + value write ----------------
__global__ void softmax_w(const float* __restrict__ scores, const int* __restrict__ sidx,
                          const float* __restrict__ cash, const float* __restrict__ hdr,
                          const float* __restrict__ bc, float* __restrict__ out) {
    __shared__ float red[1024];
    int t = threadIdx.x;
    float m = -1e30f;
    for (int i = t; i < NSTK + 1; i += 1024) {
        float v = (i == 0) ? cash[0] : scores[sidx[i - 1]];
        m = fmaxf(m, v);
    }
    red[t] = m;
    __syncthreads();
    for (int s = 512; s > 0; s >>= 1) { if (t < s) red[t] = fmaxf(red[t], red[t + s]); __syncthreads(); }
    m = red[0];
    __syncthreads();
    float sum = 0.f;
    for (int i = t; i < NSTK + 1; i += 1024) {
        float v = (i == 0) ? cash[0] : scores[sidx[i - 1]];
        sum += expf(v - m);
    }
    red[t] = sum;
    __syncthreads();
    for (int s = 512; s > 0; s >>= 1) { if (t < s) red[t] += red[t + s]; __syncthreads(); }
    float inv = 1.f / red[0];
    for (int i = t; i < NSTK + 1; i += 1024) {
        float v = (i == 0) ? cash[0] : scores[sidx[i - 1]];
        out[OUT_W + i] = expf(v - m) * inv;
    }
    if (t == 0) out[OUT_V] = hdr[6] / (float)N_NODES + bc[0];
}

extern "C" void kernel_launch(void* const* d_in, const int* in_sizes, int n_in,
                              void* d_out, int out_size, void* d_ws, size_t ws_size,
                              hipStream_t stream) {
    const float* x    = (const float*)d_in[0];
    const float* ea   = (const float*)d_in[1];
    const float* W1   = (const float*)d_in[2];
    const float* as1  = (const float*)d_in[3];
    const float* ad1  = (const float*)d_in[4];
    const float* We1  = (const float*)d_in[5];
    const float* ae1  = (const float*)d_in[6];
    const float* b1   = (const float*)d_in[7];
    const float* W2   = (const float*)d_in[8];
    const float* as2  = (const float*)d_in[9];
    const float* ad2  = (const float*)d_in[10];
    const float* We2  = (const float*)d_in[11];
    const float* ae2  = (const float*)d_in[12];
    const float* b2   = (const float*)d_in[13];
    const float* Wa   = (const float*)d_in[14];
    const float* ba   = (const float*)d_in[15];
    const float* cash = (const float*)d_in[16];
    const float* Wc   = (const float*)d_in[17];
    const float* bc   = (const float*)d_in[18];
    const int*   ei   = (const int*)d_in[19];
    const int*   sidx = (const int*)d_in[20];

    // workspace layout — all bases 16B-aligned, total ~68.5 MB (proven envelope).
    // `part` owns the 25.6 MB region the old h1 array used (h1 is now fused away).
    char* w = (char*)d_ws;
    float* hdr    = (float*)w;                    // 64 floats
    int*   deg    = (int*)(w + 256);              // N
    int*   rowoff = deg + N_NODES;                // N+4 (padded)
    EPack* epack  = (EPack*)(rowoff + N_NODES + 4);        // EF * 8B
    __half* h1pre = (__half*)(epack + EF);        // N*128 halfs
    float* ssrc1  = (float*)(h1pre + N_NODES * 128);       // N*4
    float* sdst1  = ssrc1 + N_NODES * 4;          // N*4
    float* minv   = sdst1 + N_NODES * 4;          // N*8 (m[4], inv[4] per node)
    unsigned int* part = (unsigned int*)(minv + N_NODES * 8);  // NB*NBIN32 u32 = 25.6MB
    float* h2pre  = (float*)(part + (size_t)NB * NBIN32);      // N*32
    float* ssrc2  = h2pre + N_NODES * 32;         // N
    float* sdst2  = ssrc2 + N_NODES;              // N
    float* h2     = sdst2 + N_NODES;              // N*32
    float* scores = h2 + N_NODES * 32;            // N

    float* out = (float*)d_out;

    hipMemsetAsync(hdr, 0, 256, stream);

    hist_pass<<<NB, 256, 0, stream>>>(ei, ea, part, hdr);
    rebase<<<(NBIN32 + 255) / 256, 256, 0, stream>>>(part, deg);
    scan_scalar<<<1, SCAN_T, 0, stream>>>(deg, rowoff, We1, ae1, We2, ae2, hdr);
    fill_pack<<<NB, 256, 0, stream>>>(ei, ea, rowoff, part, hdr, epack, out + OUT_EIF);

    node_lin1<<<N_NODES, 128, 0, stream>>>(x, W1, as1, ad1, h1pre, ssrc1, sdst1);
    l1_agg<<<(N_NODES + 3) / 4, 256, 0, stream>>>(epack, rowoff, ssrc1, sdst1, h1pre,
                                                  b1, W2, as2, ad2, hdr, minv,
                                                  h2pre, ssrc2, sdst2);
    alpha_write<<<2048, 256, 0, stream>>>(ei, ea, ssrc1, sdst1, minv, hdr, out + OUT_A1);
    l2_agg<<<(N_NODES + 3) / 4, 256, 0, stream>>>(epack, rowoff, ssrc2, sdst2, h2pre,
                                                  b2, hdr, h2);
    scores_value<<<(N_NODES + 255) / 256, 256, 0, stream>>>(h2, Wa, ba, Wc, scores, hdr);
    softmax_w<<<1, 1024, 0, stream>>>(scores, sidx, cash, hdr, bc, out);
}